// Round 16
// baseline (1536.434 us; speedup 1.0000x reference)
//
#include <hip/hip_runtime.h>
#include <hip/hip_bf16.h>

using u16 = unsigned short;
typedef __attribute__((ext_vector_type(4))) float f32x4;
typedef __bf16 bf16x8 __attribute__((ext_vector_type(8)));
typedef short s16x4 __attribute__((ext_vector_type(4)));
typedef short s16x8 __attribute__((ext_vector_type(8)));

#define DEVI __device__ __forceinline__

DEVI float b2f(u16 u) {
    union { unsigned i; float f; } x; x.i = ((unsigned)u) << 16; return x.f;
}
DEVI u16 f2b(float f) {
    union { float f; unsigned i; } x; x.f = f;
    unsigned r = (x.i + 0x7fffu + ((x.i >> 16) & 1u)) >> 16;
    return (u16)r;
}

// fast gelu: v * sigmoid(1.5957691 v + 0.0713548 v^3)  (tanh-form, overflow-safe)
DEVI float gelu_fast(float v) {
    float t = v * (1.5957691f + 0.0713548162f * v * v);
    return v / (1.f + __expf(-t));
}

static constexpr long long PX = 1572864LL;  // 384*4096 per batch
static constexpr long long PQ = 3145728LL;  // 768*4096 per batch
static constexpr long long PH = 6291456LL;  // 1536*4096 per batch

DEVI void gl_lds16(const u16* g, u16* l) {
    __builtin_amdgcn_global_load_lds(
        (const __attribute__((address_space(1))) unsigned int*)g,
        (__attribute__((address_space(3))) unsigned int*)l, 16, 0, 0);
}

// ---------------- all weight f32 -> bf16 conversions in ONE launch
__global__ __launch_bounds__(256)
void wconv_kernel(const float* __restrict__ qw, const float* __restrict__ kw,
                  const float* __restrict__ vw, const float* __restrict__ huw,
                  const float* __restrict__ ff1w, const float* __restrict__ ff2w,
                  u16* __restrict__ wcv)
{
    int blk = blockIdx.x;
    const float* src; u16* dst; int lb;
    if      (blk < 288)  { src = qw;   dst = wcv;           lb = blk; }
    else if (blk < 576)  { src = kw;   dst = wcv + 294912;  lb = blk - 288; }
    else if (blk < 720)  { src = vw;   dst = wcv + 589824;  lb = blk - 576; }
    else if (blk < 864)  { src = huw;  dst = wcv + 737280;  lb = blk - 720; }
    else if (blk < 1440) { src = ff1w; dst = wcv + 884736;  lb = blk - 864; }
    else                 { src = ff2w; dst = wcv + 1474560; lb = blk - 1440; }
    int i = (lb * 256 + threadIdx.x) * 4;
    f32x4 v = *(const f32x4*)(src + i);
    s16x4 o;
#pragma unroll
    for (int j = 0; j < 4; ++j) o[j] = (short)f2b(v[j]);
    *(s16x4*)(dst + i) = o;
}

// ---------------- GEMM 128x256, 512 threads (8 waves 2x4), bf16 out (+gelu)
// SINGLE contiguous LDS array (epilogue staging [64][136] overflows the A
// region into the B region by 1KB -- must be same array, like the 128^2
// kernel's lds[2][...]). 48 KB -> 3 blocks/CU = 24 waves/CU.
__global__ __launch_bounds__(512, 6)
void gemm_wide_kernel(const u16* __restrict__ A, long long strideA,
                      const u16* __restrict__ Bw,
                      const float* __restrict__ bias,
                      u16* __restrict__ C, long long strideC,
                      int K, int N, int doGelu)
{
    const int tid = threadIdx.x;
    const int lane = tid & 63;
    const int w = tid >> 6;
    const int wr = w >> 2, wc = w & 3;
    const int l15 = lane & 15, l4 = lane >> 4;
    const int bm = blockIdx.x, bn = blockIdx.y, bz = blockIdx.z;

    A += (long long)bz * strideA;
    C += (long long)bz * strideC;

    __shared__ u16 lds[128 * 64 + 256 * 64];   // contiguous: A 16KB | B 32KB
    u16* ldsA = lds;
    u16* ldsB = lds + 128 * 64;

    f32x4 acc[4][4] = {};

    auto stage = [&](int kt) {
#pragma unroll
        for (int i = 0; i < 2; ++i) {
            int cid = tid + i * 512;
            int row = cid >> 3, c8 = cid & 7;
            int c8s = c8 ^ (row & 7);
            gl_lds16(A + (long long)(bm * 128 + row) * K + kt + c8s * 8,
                     &ldsA[cid * 8]);
        }
#pragma unroll
        for (int i = 0; i < 4; ++i) {
            int cid = tid + i * 512;
            int row = cid >> 3, c8 = cid & 7;
            int c8s = c8 ^ (row & 7);
            gl_lds16(Bw + (long long)(bn * 256 + row) * K + kt + c8s * 8,
                     &ldsB[cid * 8]);
        }
    };

    auto compute = [&]() {
#pragma unroll
        for (int kk = 0; kk < 2; ++kk) {
            bf16x8 af[4], bfr[4];
#pragma unroll
            for (int mi = 0; mi < 4; ++mi) {
                int row = wr * 64 + mi * 16 + l15;
                int idx8 = (kk * 4 + l4) ^ (row & 7);
                af[mi] = *(const bf16x8*)&ldsA[row * 64 + idx8 * 8];
            }
#pragma unroll
            for (int ni = 0; ni < 4; ++ni) {
                int row = wc * 64 + ni * 16 + l15;
                int idx8 = (kk * 4 + l4) ^ (row & 7);
                bfr[ni] = *(const bf16x8*)&ldsB[row * 64 + idx8 * 8];
            }
#pragma unroll
            for (int mi = 0; mi < 4; ++mi)
#pragma unroll
                for (int ni = 0; ni < 4; ++ni)
                    acc[mi][ni] = __builtin_amdgcn_mfma_f32_16x16x32_bf16(af[mi], bfr[ni], acc[mi][ni], 0, 0, 0);
        }
    };

    stage(0);
    asm volatile("s_waitcnt vmcnt(0)" ::: "memory");
    __syncthreads();
    for (int kt = 64; kt < K; kt += 64) {
        compute();
        __syncthreads();
        stage(kt);
        asm volatile("s_waitcnt vmcnt(0)" ::: "memory");
        __syncthreads();
    }
    compute();

    // epilogue: 4 passes (2 row-halves x 2 col-halves), [64][136] staging
    u16* st = lds;   // 17.4 KB, safely inside the 48 KB contiguous array
#pragma unroll
    for (int p = 0; p < 4; ++p) {
        int rp = p >> 1, cp = p & 1;
        __syncthreads();
        if (wr == rp && (wc >> 1) == cp) {
#pragma unroll
            for (int ni = 0; ni < 4; ++ni) {
                int colL = (wc & 1) * 64 + ni * 16 + l15;
                float bv = bias ? bias[bn * 256 + cp * 128 + colL] : 0.f;
#pragma unroll
                for (int mi = 0; mi < 4; ++mi) {
#pragma unroll
                    for (int r = 0; r < 4; ++r) {
                        float v = acc[mi][ni][r] + bv;
                        if (doGelu) v = gelu_fast(v);
                        st[(mi * 16 + l4 * 4 + r) * 136 + colL] = f2b(v);
                    }
                }
            }
        }
        __syncthreads();
        int lr = tid >> 3, q = tid & 7;
        const u16* src = st + lr * 136 + q * 16;
        u16* dst = C + (long long)(bm * 128 + rp * 64 + lr) * N + bn * 256 + cp * 128 + q * 16;
        *(s16x8*)(dst)     = *(const s16x8*)(src);
        *(s16x8*)(dst + 8) = *(const s16x8*)(src + 8);
    }
}

// ---------------- GEMM 128x128 (R10 structure) for N=384-class + f32 epilogue
__global__ __launch_bounds__(256, 4)
void gemm_bt_kernel(const u16* __restrict__ A, long long strideA,
                    const u16* __restrict__ Bw, long long strideB,
                    const float* __restrict__ bias,
                    u16* __restrict__ C, long long strideC,
                    float* __restrict__ Cf,
                    const u16* __restrict__ addT, long long strideAdd,
                    int K, int N, int doGelu)
{
    const int tid = threadIdx.x;
    const int lane = tid & 63;
    const int wv = tid >> 6;
    const int wr = wv >> 1, wc = wv & 1;
    const int l15 = lane & 15, l4 = lane >> 4;
    const int bm = blockIdx.x, bn = blockIdx.y, bz = blockIdx.z;

    A  += (long long)bz * strideA;
    Bw += (long long)bz * strideB;
    if (C)    C    += (long long)bz * strideC;
    if (Cf)   Cf   += (long long)bz * strideC;
    if (addT) addT += (long long)bz * strideAdd;

    __shared__ u16 lds[2][128 * 64];   // 32 KB

    f32x4 acc[4][4] = {};

    auto stage = [&](int kt) {
#pragma unroll
        for (int i = 0; i < 4; ++i) {
            int cid = tid + i * 256;
            int row = cid >> 3, c8 = cid & 7;
            int c8s = c8 ^ (row & 7);
            gl_lds16(A + (long long)(bm * 128 + row) * K + kt + c8s * 8,
                     &lds[0][cid * 8]);
        }
#pragma unroll
        for (int i = 0; i < 4; ++i) {
            int cid = tid + i * 256;
            int row = cid >> 3, c8 = cid & 7;
            int c8s = c8 ^ (row & 7);
            gl_lds16(Bw + (long long)(bn * 128 + row) * K + kt + c8s * 8,
                     &lds[1][cid * 8]);
        }
    };

    auto compute = [&]() {
#pragma unroll
        for (int kk = 0; kk < 2; ++kk) {
            bf16x8 af[4], bfr[4];
#pragma unroll
            for (int mi = 0; mi < 4; ++mi) {
                int row = wr * 64 + mi * 16 + l15;
                int idx8 = (kk * 4 + l4) ^ (row & 7);
                af[mi] = *(const bf16x8*)&lds[0][row * 64 + idx8 * 8];
            }
#pragma unroll
            for (int ni = 0; ni < 4; ++ni) {
                int row = wc * 64 + ni * 16 + l15;
                int idx8 = (kk * 4 + l4) ^ (row & 7);
                bfr[ni] = *(const bf16x8*)&lds[1][row * 64 + idx8 * 8];
            }
#pragma unroll
            for (int mi = 0; mi < 4; ++mi)
#pragma unroll
                for (int ni = 0; ni < 4; ++ni)
                    acc[mi][ni] = __builtin_amdgcn_mfma_f32_16x16x32_bf16(af[mi], bfr[ni], acc[mi][ni], 0, 0, 0);
        }
    };

    stage(0);
    asm volatile("s_waitcnt vmcnt(0)" ::: "memory");
    __syncthreads();
    for (int kt = 64; kt < K; kt += 64) {
        compute();
        __syncthreads();
        stage(kt);
        asm volatile("s_waitcnt vmcnt(0)" ::: "memory");
        __syncthreads();
    }
    compute();

    if (!Cf) {
        u16* st = &lds[0][0];            // [64][136]
#pragma unroll
        for (int p = 0; p < 2; ++p) {
            __syncthreads();
            if (wr == p) {
#pragma unroll
                for (int ni = 0; ni < 4; ++ni) {
                    int colL = wc * 64 + ni * 16 + l15;
                    float bv = bias ? bias[bn * 128 + colL] : 0.f;
#pragma unroll
                    for (int mi = 0; mi < 4; ++mi) {
#pragma unroll
                        for (int r = 0; r < 4; ++r) {
                            float v = acc[mi][ni][r] + bv;
                            if (doGelu) v = gelu_fast(v);
                            st[(mi * 16 + l4 * 4 + r) * 136 + colL] = f2b(v);
                        }
                    }
                }
            }
            __syncthreads();
            int lr = tid >> 2, q = tid & 3;
            const u16* src = st + lr * 136 + q * 32;
            u16* dst = C + (long long)(bm * 128 + p * 64 + lr) * N + bn * 128 + q * 32;
#pragma unroll
            for (int j = 0; j < 4; ++j)
                *(s16x8*)(dst + j * 8) = *(const s16x8*)(src + j * 8);
        }
    } else {
        float* stf = (float*)&lds[0][0];   // [32][132]
#pragma unroll
        for (int p = 0; p < 4; ++p) {
            __syncthreads();
            if (wc == (p >> 1)) {
#pragma unroll
                for (int nj = 0; nj < 2; ++nj) {
                    int ni = (p & 1) * 2 + nj;
                    int colL = wc * 64 + ni * 16 + l15;
                    int lc = nj * 16 + l15;
                    float bv = bias ? bias[bn * 128 + colL] : 0.f;
#pragma unroll
                    for (int mi = 0; mi < 4; ++mi) {
                        int row0 = wr * 64 + mi * 16 + l4 * 4;
#pragma unroll
                        for (int r = 0; r < 4; ++r) {
                            float v = acc[mi][ni][r] + bv
                                    + b2f(addT[(long long)(bm * 128 + row0 + r) * N + bn * 128 + colL]);
                            stf[lc * 132 + row0 + r] = v;
                        }
                    }
                }
            }
            __syncthreads();
            int lc = tid >> 3, q = tid & 7;
            float* dst = Cf + (long long)(bn * 128 + p * 32 + lc) * 4096 + bm * 128 + q * 16;
            const float* src = stf + lc * 132 + q * 16;
#pragma unroll
            for (int j = 0; j < 4; ++j)
                *(f32x4*)(dst + j * 4) = *(const f32x4*)(src + j * 4);
        }
    }
}

// ---------------- per-batch sum / sumsq partials over 1572864 f32 elems
__global__ __launch_bounds__(256)
void stats_part_kernel(const float* __restrict__ x, float* __restrict__ part)
{
    int b = blockIdx.x, cb = blockIdx.y, t = threadIdx.x;
    const float* p = x + (long long)b * PX + (long long)cb * 49152;
    float s = 0.f, q = 0.f;
    for (int i = 0; i < 48; ++i) {
        f32x4 v = *(const f32x4*)(p + (i * 256 + t) * 4);
#pragma unroll
        for (int j = 0; j < 4; ++j) { s += v[j]; q += v[j] * v[j]; }
    }
    for (int off = 32; off; off >>= 1) { s += __shfl_down(s, off); q += __shfl_down(q, off); }
    __shared__ float rs[4], rq[4];
    if ((t & 63) == 0) { rs[t >> 6] = s; rq[t >> 6] = q; }
    __syncthreads();
    if (t == 0) {
        part[(b * 32 + cb) * 2 + 0] = rs[0] + rs[1] + rs[2] + rs[3];
        part[(b * 32 + cb) * 2 + 1] = rq[0] + rq[1] + rq[2] + rq[3];
    }
}

__global__ void stats_fin_kernel(const float* __restrict__ part, float* __restrict__ mu, float* __restrict__ rsg)
{
    int b = blockIdx.x, l = threadIdx.x;
    float s = l < 32 ? part[(b * 32 + l) * 2 + 0] : 0.f;
    float q = l < 32 ? part[(b * 32 + l) * 2 + 1] : 0.f;
    for (int off = 32; off; off >>= 1) { s += __shfl_down(s, off); q += __shfl_down(q, off); }
    if (l == 0) {
        float m = s / 1572864.f;
        float v = q / 1572864.f - m * m; v = fmaxf(v, 0.f);
        mu[b] = m; rsg[b] = rsqrtf(v + 1e-5f);
    }
}

// ---------------- LN1 apply (f32 src, d-major) -> T-layout bf16
__global__ __launch_bounds__(256)
void ln_apply_T_kernel(const float* __restrict__ src, const float* __restrict__ w, const float* __restrict__ bb,
                       const float* __restrict__ mu, const float* __restrict__ rsg, u16* __restrict__ dstT)
{
    int nt = blockIdx.x, dt = blockIdx.y, b = blockIdx.z;
    int t = threadIdx.x, tx = t & 63, ty = t >> 6;
    __shared__ float tile[64][65];
    float m = mu[b], r = rsg[b];
    const long long base = (long long)b * PX;
#pragma unroll 4
    for (int i = 0; i < 16; ++i) {
        int dy = ty + i * 4;
        int d = dt * 64 + dy, n = nt * 64 + tx;
        long long widx = (long long)d * 4096 + n;
        tile[dy][tx] = (src[base + widx] - m) * r * w[widx] + bb[widx];
    }
    __syncthreads();
#pragma unroll 4
    for (int i = 0; i < 16; ++i) {
        int ny = ty + i * 4;
        int n = nt * 64 + ny, d = dt * 64 + tx;
        dstT[base + (long long)n * 384 + d] = f2b(tile[tx][ny]);
    }
}

// ---------------- row softmax over 768 contiguous channels (Q), in place
__global__ __launch_bounds__(256)
void softmax_rows_kernel(u16* __restrict__ QT)
{
    long long row = (long long)blockIdx.x * 4 + (threadIdx.x >> 6);
    int lane = threadIdx.x & 63;
    u16* p = QT + row * 768;
    float v[12];
#pragma unroll
    for (int g = 0; g < 3; ++g) {
        s16x4 a = *(const s16x4*)(p + g * 256 + lane * 4);
#pragma unroll
        for (int j = 0; j < 4; ++j) v[g * 4 + j] = b2f((u16)a[j]);
    }
    float m = -1e30f;
#pragma unroll
    for (int j = 0; j < 12; ++j) m = fmaxf(m, v[j]);
    for (int off = 32; off; off >>= 1) m = fmaxf(m, __shfl_xor(m, off));
    float s = 0.f;
#pragma unroll
    for (int j = 0; j < 12; ++j) { v[j] = __expf(v[j] - m); s += v[j]; }
    for (int off = 32; off; off >>= 1) s += __shfl_xor(s, off);
    float inv = 1.f / s;
#pragma unroll
    for (int g = 0; g < 3; ++g) {
        s16x4 o;
#pragma unroll
        for (int j = 0; j < 4; ++j) o[j] = (short)f2b(v[g * 4 + j] * inv);
        *(s16x4*)(p + g * 256 + lane * 4) = o;
    }
}

// ---------------- KV partials via MFMA, no-max exp (inputs bounded), CHUNK=128
__global__ __launch_bounds__(256)
void kv_part_kernel(const u16* __restrict__ KT, const u16* __restrict__ VT,
                    u16* __restrict__ KVp, float* __restrict__ sp)
{
    const int ch = blockIdx.x, h = blockIdx.y, b = blockIdx.z;
    const int t = threadIdx.x;
    const int lane = t & 63, w = t >> 6;

    __shared__ u16 kraw[128 * 64];
    __shared__ u16 eKT[64 * 128];
    __shared__ u16 Vt[32 * 128];
    __shared__ float reds[4][64];

    const u16* Kp = KT + (long long)b * PQ + (long long)(ch * 128) * 768 + h * 64;
    const u16* Vp = VT + (long long)b * PX + (long long)(ch * 128) * 384 + h * 32;

#pragma unroll
    for (int pass = 0; pass < 4; ++pass) {
        int cid = t + pass * 256;
        int row = cid >> 3, c8 = cid & 7;
        gl_lds16(Kp + (long long)row * 768 + c8 * 8, kraw + cid * 8);
    }

    {
        int v0 = (t & 7) * 4;
#pragma unroll
        for (int pass = 0; pass < 4; ++pass) {
            int n = (t >> 3) + pass * 32;
            s16x4 v4 = *(const s16x4*)(Vp + (long long)n * 384 + v0);
#pragma unroll
            for (int j = 0; j < 4; ++j) {
                int row = v0 + j;
                Vt[row * 128 + (n ^ ((row & 7) << 3))] = (u16)v4[j];
            }
        }
    }

    asm volatile("s_waitcnt vmcnt(0)" ::: "memory");
    __syncthreads();

    const int c = lane;
    {
        float s = 0.f;
        const int swz = (c & 7) << 3;
#pragma unroll
        for (int r8 = 0; r8 < 4; ++r8) {
            int rbase = w * 32 + r8 * 8;
            s16x8 buf;
#pragma unroll
            for (int j = 0; j < 8; ++j) {
                float e = __expf(b2f(kraw[(rbase + j) * 64 + c]));
                s += e;
                buf[j] = (short)f2b(e);
            }
            *(s16x8*)&eKT[c * 128 + (rbase ^ swz)] = buf;
        }
        reds[w][c] = s;
    }
    __syncthreads();

    if (t < 64)
        sp[((long long)(b * 12 + h) * 32 + ch) * 64 + t] =
            reds[0][t] + reds[1][t] + reds[2][t] + reds[3][t];

    const int l15 = lane & 15, l4 = lane >> 4;
    const int qrow = w * 16 + l15;
    const int sa = (qrow & 7) << 3;
    const int v0row = l15, v1row = 16 + l15;
    const int s0 = (v0row & 7) << 3, s1 = (v1row & 7) << 3;
    f32x4 acc0 = {}, acc1 = {};
#pragma unroll
    for (int ns = 0; ns < 4; ++ns) {
        int na = ns * 32 + l4 * 8;
        bf16x8 a  = *(const bf16x8*)&eKT[qrow * 128 + (na ^ sa)];
        bf16x8 b0 = *(const bf16x8*)&Vt[v0row * 128 + (na ^ s0)];
        bf16x8 b1 = *(const bf16x8*)&Vt[v1row * 128 + (na ^ s1)];
        acc0 = __builtin_amdgcn_mfma_f32_16x16x32_bf16(a, b0, acc0, 0, 0, 0);
        acc1 = __builtin_amdgcn_mfma_f32_16x16x32_bf16(a, b1, acc1, 0, 0, 0);
    }
    u16* Kb = KVp + ((long long)(b * 12 + h) * 32 + ch) * 2048;
#pragma unroll
    for (int r = 0; r < 4; ++r) {
        int q = w * 16 + l4 * 4 + r;
        Kb[q * 32 + l15]      = f2b(acc0[r]);
        Kb[q * 32 + 16 + l15] = f2b(acc1[r]);
    }
}

// ---------------- merge 32 KV partials -> WeffT (768 x 384 per batch)
__global__ __launch_bounds__(256)
void kv_fin_kernel(const u16* __restrict__ KVp, const float* __restrict__ sp,
                   u16* __restrict__ WeffT)
{
    const int h = blockIdx.x, b = blockIdx.y;
    const int t = threadIdx.x;
    __shared__ float fac[64];
    __shared__ float kvt[32][64];

    const long long pb = (long long)(b * 12 + h) * 32;
    if (t < 64) {
        float s = 0.f;
#pragma unroll
        for (int ch = 0; ch < 32; ++ch) s += sp[(pb + ch) * 64 + t];
        fac[t] = 1.f / (s * 4096.f);
    }
    __syncthreads();

    const int v0 = (t & 3) * 8, q = t >> 2;
    float acc[8] = {};
#pragma unroll
    for (int ch = 0; ch < 32; ++ch) {
        s16x8 kv8 = *(const s16x8*)&KVp[(pb + ch) * 2048 + q * 32 + v0];
#pragma unroll
        for (int j = 0; j < 8; ++j) acc[j] += b2f((u16)kv8[j]);
    }
    float fq = fac[q];
#pragma unroll
    for (int j = 0; j < 8; ++j) kvt[v0 + j][q] = acc[j] * fq;
    __syncthreads();

    u16* Wb = WeffT + (long long)b * 294912;
    for (int i = t; i < 64 * 384; i += 256) {
        int qq = i / 384, cc = i % 384;
        int cv = cc - h * 32;
        float val = (cv >= 0 && cv < 32) ? kvt[cv][qq] : 0.f;
        Wb[(long long)(h * 64 + qq) * 384 + cc] = f2b(val);
    }
}

// ---------------- transpose LN2 weight/bias (f32 d-major) -> bf16 T-layout
__global__ __launch_bounds__(256)
void wtrans_kernel(const float* __restrict__ w, const float* __restrict__ bb,
                   u16* __restrict__ wT, u16* __restrict__ bT)
{
    int nt = blockIdx.x, dt = blockIdx.y;
    const float* src = blockIdx.z ? bb : w;
    u16* dst = blockIdx.z ? bT : wT;
    int t = threadIdx.x, tx = t & 63, ty = t >> 6;
    __shared__ float tile[64][65];
#pragma unroll 4
    for (int i = 0; i < 16; ++i) {
        int dy = ty + i * 4;
        tile[dy][tx] = src[(long long)(dt * 64 + dy) * 4096 + nt * 64 + tx];
    }
    __syncthreads();
#pragma unroll 4
    for (int i = 0; i < 16; ++i) {
        int ny = ty + i * 4;
        dst[(long long)(nt * 64 + ny) * 384 + dt * 64 + tx] = f2b(tile[tx][ny]);
    }
}

// ---------------- residual 1: sT(T-layout bf16) = x^T + attnT, + LN2 partials
__global__ __launch_bounds__(256)
void resid1T_kernel(const float* __restrict__ x, const u16* __restrict__ attnT,
                    u16* __restrict__ sT, float* __restrict__ part2)
{
    int nt = blockIdx.x, dt = blockIdx.y, b = blockIdx.z;
    int t = threadIdx.x, tx = t & 63, ty = t >> 6;
    __shared__ float tile[64][65];
    const long long base = (long long)b * PX;
#pragma unroll 4
    for (int i = 0; i < 16; ++i) {
        int dy = ty + i * 4;
        tile[dy][tx] = x[base + (long long)(dt * 64 + dy) * 4096 + nt * 64 + tx];
    }
    __syncthreads();
    float ps = 0.f, pq = 0.f;
#pragma unroll 4
    for (int i = 0; i < 16; ++i) {
        int ny = ty + i * 4;
        long long idx = base + (long long)(nt * 64 + ny) * 384 + dt * 64 + tx;
        float val = tile[tx][ny] + b2f(attnT[idx]);
        sT[idx] = f2b(val);
        ps += val; pq += val * val;
    }
    for (int off = 32; off; off >>= 1) { ps += __shfl_down(ps, off); pq += __shfl_down(pq, off); }
    __shared__ float rs[4], rq[4];
    if ((t & 63) == 0) { rs[t >> 6] = ps; rq[t >> 6] = pq; }
    __syncthreads();
    if (t == 0) {
        int bid = (b * 6 + dt) * 64 + nt;
        part2[bid * 2 + 0] = rs[0] + rs[1] + rs[2] + rs[3];
        part2[bid * 2 + 1] = rq[0] + rq[1] + rq[2] + rq[3];
    }
}

__global__ __launch_bounds__(256)
void stats_fin2_kernel(const float* __restrict__ part2, float* __restrict__ mu, float* __restrict__ rsg)
{
    int b = blockIdx.x, t = threadIdx.x;
    float s = 0.f, q = 0.f;
    for (int i = t; i < 384; i += 256) { s += part2[(b * 384 + i) * 2]; q += part2[(b * 384 + i) * 2 + 1]; }
    for (int off = 32; off; off >>= 1) { s += __shfl_down(s, off); q += __shfl_down(q, off); }
    __shared__ float rs[4], rq[4];
    if ((t & 63) == 0) { rs[t >> 6] = s; rq[t >> 6] = q; }
    __syncthreads();
    if (t == 0) {
        float S = rs[0] + rs[1] + rs[2] + rs[3], Q = rq[0] + rq[1] + rq[2] + rq[3];
        float m = S / 1572864.f;
        float v = Q / 1572864.f - m * m; v = fmaxf(v, 0.f);
        mu[b] = m; rsg[b] = rsqrtf(v + 1e-5f);
    }
}

// ---------------- LN2 apply: elementwise T-layout, all bf16
__global__ __launch_bounds__(256)
void ln2_apply_kernel(const u16* __restrict__ sT, const u16* __restrict__ wT, const u16* __restrict__ bT,
                      const float* __restrict__ mu, const float* __restrict__ rsg, u16* __restrict__ x2T)
{
    int blk = blockIdx.x, b = blockIdx.y, t = threadIdx.x;
    float m = mu[b], r = rsg[b];
    long long wi = (long long)blk * 2048 + t * 8;
    long long gi = (long long)b * PX + wi;
    s16x8 sv = *(const s16x8*)(sT + gi);
    s16x8 wv = *(const s16x8*)(wT + wi);
    s16x8 bv = *(const s16x8*)(bT + wi);
    s16x8 o;
#pragma unroll
    for (int j = 0; j < 8; ++j)
        o[j] = (short)f2b((b2f((u16)sv[j]) - m) * r * b2f((u16)wv[j]) + b2f((u16)bv[j]));
    *(s16x8*)(x2T + gi) = o;
}

extern "C" void kernel_launch(void* const* d_in, const int* in_sizes, int n_in,
                              void* d_out, int out_size, void* d_ws, size_t ws_size,
                              hipStream_t stream)
{
    const float* x    = (const float*)d_in[0];
    const float* ln1w = (const float*)d_in[1];
    const float* ln1b = (const float*)d_in[2];
    const float* qw   = (const float*)d_in[3];
    const float* qb   = (const float*)d_in[4];
    const float* kw   = (const float*)d_in[5];
    const float* kb   = (const float*)d_in[6];
    const float* vw   = (const float*)d_in[7];
    const float* vb   = (const float*)d_in[8];
    const float* huw  = (const float*)d_in[9];
    const float* hub  = (const float*)d_in[10];
    const float* ln2w = (const float*)d_in[11];
    const float* ln2b = (const float*)d_in[12];
    const float* ff1w = (const float*)d_in[13];
    const float* ff1b = (const float*)d_in[14];
    const float* ff2w = (const float*)d_in[15];
    const float* ff2b = (const float*)d_in[16];
    float* out = (float*)d_out;

    char* ws = (char*)d_ws;
    u16*   aT    = (u16*)(ws + 0);                 //  50.3 MB region A
    u16*   QT    = (u16*)(ws + 50331648LL);        // 100.7 MB region B
    u16*   KT    = (u16*)(ws + 150994944LL);       // 100.7 MB region C
    u16*   VT    = (u16*)(ws + 251658240LL);       //  50.3 MB region D
    u16*   WeffT = (u16*)(ws + 301989888LL);       //   9.4 MB region E
    u16*   wcv   = (u16*)(ws + 311427072LL);       //   4.1 MB
    float* fbuf  = (float*)(ws + 315555840LL);     //  ~64 KB

    // region A overlays (aT dead after QKV GEMMs):
    u16*   KVp    = (u16*)(ws + 0);                // 25,165,824 B
    float* sp     = (float*)(ws + 25165824LL);     //  1,572,864 B
    u16*   WcombB = (u16*)(ws + 27525120LL);       //  9,437,184 B

    // region C overlays (KT dead after kv_part):
    u16* sT = KT;                                       // 50.3 MB
    u16* wT = (u16*)(ws + 150994944LL + 50331648LL);    //  3.1 MB
    u16* bT = (u16*)(ws + 150994944LL + 53477376LL);    //  3.1 MB
    u16* g8 = KT;                                       // 100.66 MB (after ln2_apply)

    u16* x2T   = QT;
    u16* attnT = VT;

    u16* qwB   = wcv;
    u16* kwB   = wcv + 294912;
    u16* vwB   = wcv + 589824;
    u16* huwB  = wcv + 737280;
    u16* ff1wB = wcv + 884736;
    u16* ff2wB = wcv + 1474560;

    float* part1 = fbuf;
    float* mu1   = fbuf + 1024;
    float* rs1   = fbuf + 1040;
    float* part2 = fbuf + 1056;
    float* mu2   = part2 + 12288;
    float* rs2   = mu2 + 16;

    wconv_kernel<<<2016, 256, 0, stream>>>(qw, kw, vw, huw, ff1w, ff2w, wcv);

    stats_part_kernel<<<dim3(16, 32), 256, 0, stream>>>(x, part1);
    stats_fin_kernel<<<16, 64, 0, stream>>>(part1, mu1, rs1);
    ln_apply_T_kernel<<<dim3(64, 6, 16), 256, 0, stream>>>(x, ln1w, ln1b, mu1, rs1, aT);

    // Q, K: wide 128x256 tiles (512 threads); V: 128x128
    gemm_wide_kernel<<<dim3(32, 3, 16), 512, 0, stream>>>(aT, PX, qwB, qb, QT, PQ, 384, 768, 0);
    gemm_wide_kernel<<<dim3(32, 3, 16), 512, 0, stream>>>(aT, PX, kwB, kb, KT, PQ, 384, 768, 0);
    gemm_bt_kernel<<<dim3(32, 3, 16), 256, 0, stream>>>(aT, PX, vwB, 0, vb, VT, PX, nullptr, nullptr, 0, 384, 384, 0);

    softmax_rows_kernel<<<16384, 256, 0, stream>>>(QT);

    kv_part_kernel<<<dim3(32, 12, 16), 256, 0, stream>>>(KT, VT, KVp, sp);
    kv_fin_kernel<<<dim3(12, 16), 256, 0, stream>>>(KVp, sp, WeffT);

    wtrans_kernel<<<dim3(64, 6, 2), 256, 0, stream>>>(ln2w, ln2b, wT, bT);

    gemm_bt_kernel<<<dim3(3, 6, 16), 256, 0, stream>>>(huwB, 0, WeffT, 294912, nullptr, WcombB, 294912, nullptr, nullptr, 0, 384, 768, 0);

    gemm_bt_kernel<<<dim3(32, 3, 16), 256, 0, stream>>>(QT, PQ, WcombB, 294912, hub, attnT, PX, nullptr, nullptr, 0, 768, 384, 0);

    resid1T_kernel<<<dim3(64, 6, 16), 256, 0, stream>>>(x, attnT, sT, part2);
    stats_fin2_kernel<<<16, 256, 0, stream>>>(part2, mu2, rs2);
    ln2_apply_kernel<<<dim3(768, 16), 256, 0, stream>>>(sT, wT, bT, mu2, rs2, x2T);

    // FFN in 2 chunks of 8 batches; FF1 wide (N=1536), FF2 128x128 f32-out
    for (int c = 0; c < 2; ++c) {
        gemm_wide_kernel<<<dim3(32, 6, 8), 512, 0, stream>>>(
            x2T + (long long)c * 8 * PX, PX, ff1wB, ff1b,
            g8, PH, 384, 1536, 1);
        gemm_bt_kernel<<<dim3(32, 3, 8), 256, 0, stream>>>(
            g8, PH, ff2wB, 0, ff2b,
            nullptr, PX, out + (long long)c * 8 * PX,
            x2T + (long long)c * 8 * PX, PX, 1536, 384, 0);
    }
}

// Round 17
// 807.324 us; speedup vs baseline: 1.9031x; 1.9031x over previous
//
#include <hip/hip_runtime.h>
#include <hip/hip_bf16.h>

using u16 = unsigned short;
typedef __attribute__((ext_vector_type(4))) float f32x4;
typedef __bf16 bf16x8 __attribute__((ext_vector_type(8)));
typedef short s16x4 __attribute__((ext_vector_type(4)));
typedef short s16x8 __attribute__((ext_vector_type(8)));

#define DEVI __device__ __forceinline__

DEVI float b2f(u16 u) {
    union { unsigned i; float f; } x; x.i = ((unsigned)u) << 16; return x.f;
}
DEVI u16 f2b(float f) {
    union { float f; unsigned i; } x; x.f = f;
    unsigned r = (x.i + 0x7fffu + ((x.i >> 16) & 1u)) >> 16;
    return (u16)r;
}

// fast gelu: v * sigmoid(1.5957691 v + 0.0713548 v^3)  (tanh-form, overflow-safe)
DEVI float gelu_fast(float v) {
    float t = v * (1.5957691f + 0.0713548162f * v * v);
    return v / (1.f + __expf(-t));
}

static constexpr long long PX = 1572864LL;  // 384*4096 per batch
static constexpr long long PQ = 3145728LL;  // 768*4096 per batch
static constexpr long long PH = 6291456LL;  // 1536*4096 per batch

DEVI void gl_lds16(const u16* g, u16* l) {
    __builtin_amdgcn_global_load_lds(
        (const __attribute__((address_space(1))) unsigned int*)g,
        (__attribute__((address_space(3))) unsigned int*)l, 16, 0, 0);
}

// ---------------- all weight f32 -> bf16 conversions in ONE launch
__global__ __launch_bounds__(256)
void wconv_kernel(const float* __restrict__ qw, const float* __restrict__ kw,
                  const float* __restrict__ vw, const float* __restrict__ huw,
                  const float* __restrict__ ff1w, const float* __restrict__ ff2w,
                  u16* __restrict__ wcv)
{
    int blk = blockIdx.x;
    const float* src; u16* dst; int lb;
    if      (blk < 288)  { src = qw;   dst = wcv;           lb = blk; }
    else if (blk < 576)  { src = kw;   dst = wcv + 294912;  lb = blk - 288; }
    else if (blk < 720)  { src = vw;   dst = wcv + 589824;  lb = blk - 576; }
    else if (blk < 864)  { src = huw;  dst = wcv + 737280;  lb = blk - 720; }
    else if (blk < 1440) { src = ff1w; dst = wcv + 884736;  lb = blk - 864; }
    else                 { src = ff2w; dst = wcv + 1474560; lb = blk - 1440; }
    int i = (lb * 256 + threadIdx.x) * 4;
    f32x4 v = *(const f32x4*)(src + i);
    s16x4 o;
#pragma unroll
    for (int j = 0; j < 4; ++j) o[j] = (short)f2b(v[j]);
    *(s16x4*)(dst + i) = o;
}

// ---------------- GEMM 128x256, 512 threads (8 waves 2x4), bf16 out (+gelu)
// launch_bounds (512,4): VGPR cap 128 fits acc(64)+frags(32)+addr (the
// (512,6) variant capped at ~85 and SPILLED the accumulators -> 410MB
// scratch traffic, R16 regression). 2 blocks/CU = 16 waves/CU.
__global__ __launch_bounds__(512, 4)
void gemm_wide_kernel(const u16* __restrict__ A, long long strideA,
                      const u16* __restrict__ Bw,
                      const float* __restrict__ bias,
                      u16* __restrict__ C, long long strideC,
                      int K, int N, int doGelu)
{
    const int tid = threadIdx.x;
    const int lane = tid & 63;
    const int w = tid >> 6;
    const int wr = w >> 2, wc = w & 3;
    const int l15 = lane & 15, l4 = lane >> 4;
    const int bm = blockIdx.x, bn = blockIdx.y, bz = blockIdx.z;

    A += (long long)bz * strideA;
    C += (long long)bz * strideC;

    __shared__ u16 lds[128 * 64 + 256 * 64];   // contiguous: A 16KB | B 32KB
    u16* ldsA = lds;
    u16* ldsB = lds + 128 * 64;

    f32x4 acc[4][4] = {};

    auto stage = [&](int kt) {
#pragma unroll
        for (int i = 0; i < 2; ++i) {
            int cid = tid + i * 512;
            int row = cid >> 3, c8 = cid & 7;
            int c8s = c8 ^ (row & 7);
            gl_lds16(A + (long long)(bm * 128 + row) * K + kt + c8s * 8,
                     &ldsA[cid * 8]);
        }
#pragma unroll
        for (int i = 0; i < 4; ++i) {
            int cid = tid + i * 512;
            int row = cid >> 3, c8 = cid & 7;
            int c8s = c8 ^ (row & 7);
            gl_lds16(Bw + (long long)(bn * 256 + row) * K + kt + c8s * 8,
                     &ldsB[cid * 8]);
        }
    };

    auto compute = [&]() {
#pragma unroll
        for (int kk = 0; kk < 2; ++kk) {
            bf16x8 af[4], bfr[4];
#pragma unroll
            for (int mi = 0; mi < 4; ++mi) {
                int row = wr * 64 + mi * 16 + l15;
                int idx8 = (kk * 4 + l4) ^ (row & 7);
                af[mi] = *(const bf16x8*)&ldsA[row * 64 + idx8 * 8];
            }
#pragma unroll
            for (int ni = 0; ni < 4; ++ni) {
                int row = wc * 64 + ni * 16 + l15;
                int idx8 = (kk * 4 + l4) ^ (row & 7);
                bfr[ni] = *(const bf16x8*)&ldsB[row * 64 + idx8 * 8];
            }
#pragma unroll
            for (int mi = 0; mi < 4; ++mi)
#pragma unroll
                for (int ni = 0; ni < 4; ++ni)
                    acc[mi][ni] = __builtin_amdgcn_mfma_f32_16x16x32_bf16(af[mi], bfr[ni], acc[mi][ni], 0, 0, 0);
        }
    };

    stage(0);
    asm volatile("s_waitcnt vmcnt(0)" ::: "memory");
    __syncthreads();
    for (int kt = 64; kt < K; kt += 64) {
        compute();
        __syncthreads();
        stage(kt);
        asm volatile("s_waitcnt vmcnt(0)" ::: "memory");
        __syncthreads();
    }
    compute();

    // epilogue: 4 passes (2 row-halves x 2 col-halves), [64][136] staging
    u16* st = lds;   // 17.4 KB, inside the 48 KB contiguous array
#pragma unroll
    for (int p = 0; p < 4; ++p) {
        int rp = p >> 1, cp = p & 1;
        __syncthreads();
        if (wr == rp && (wc >> 1) == cp) {
#pragma unroll
            for (int ni = 0; ni < 4; ++ni) {
                int colL = (wc & 1) * 64 + ni * 16 + l15;
                float bv = bias ? bias[bn * 256 + cp * 128 + colL] : 0.f;
#pragma unroll
                for (int mi = 0; mi < 4; ++mi) {
#pragma unroll
                    for (int r = 0; r < 4; ++r) {
                        float v = acc[mi][ni][r] + bv;
                        if (doGelu) v = gelu_fast(v);
                        st[(mi * 16 + l4 * 4 + r) * 136 + colL] = f2b(v);
                    }
                }
            }
        }
        __syncthreads();
        int lr = tid >> 3, q = tid & 7;
        const u16* src = st + lr * 136 + q * 16;
        u16* dst = C + (long long)(bm * 128 + rp * 64 + lr) * N + bn * 256 + cp * 128 + q * 16;
        *(s16x8*)(dst)     = *(const s16x8*)(src);
        *(s16x8*)(dst + 8) = *(const s16x8*)(src + 8);
    }
}

// ---------------- GEMM 128x128 (R10 structure) for N=384-class + f32 epilogue
__global__ __launch_bounds__(256, 4)
void gemm_bt_kernel(const u16* __restrict__ A, long long strideA,
                    const u16* __restrict__ Bw, long long strideB,
                    const float* __restrict__ bias,
                    u16* __restrict__ C, long long strideC,
                    float* __restrict__ Cf,
                    const u16* __restrict__ addT, long long strideAdd,
                    int K, int N, int doGelu)
{
    const int tid = threadIdx.x;
    const int lane = tid & 63;
    const int wv = tid >> 6;
    const int wr = wv >> 1, wc = wv & 1;
    const int l15 = lane & 15, l4 = lane >> 4;
    const int bm = blockIdx.x, bn = blockIdx.y, bz = blockIdx.z;

    A  += (long long)bz * strideA;
    Bw += (long long)bz * strideB;
    if (C)    C    += (long long)bz * strideC;
    if (Cf)   Cf   += (long long)bz * strideC;
    if (addT) addT += (long long)bz * strideAdd;

    __shared__ u16 lds[2][128 * 64];   // 32 KB

    f32x4 acc[4][4] = {};

    auto stage = [&](int kt) {
#pragma unroll
        for (int i = 0; i < 4; ++i) {
            int cid = tid + i * 256;
            int row = cid >> 3, c8 = cid & 7;
            int c8s = c8 ^ (row & 7);
            gl_lds16(A + (long long)(bm * 128 + row) * K + kt + c8s * 8,
                     &lds[0][cid * 8]);
        }
#pragma unroll
        for (int i = 0; i < 4; ++i) {
            int cid = tid + i * 256;
            int row = cid >> 3, c8 = cid & 7;
            int c8s = c8 ^ (row & 7);
            gl_lds16(Bw + (long long)(bn * 128 + row) * K + kt + c8s * 8,
                     &lds[1][cid * 8]);
        }
    };

    auto compute = [&]() {
#pragma unroll
        for (int kk = 0; kk < 2; ++kk) {
            bf16x8 af[4], bfr[4];
#pragma unroll
            for (int mi = 0; mi < 4; ++mi) {
                int row = wr * 64 + mi * 16 + l15;
                int idx8 = (kk * 4 + l4) ^ (row & 7);
                af[mi] = *(const bf16x8*)&lds[0][row * 64 + idx8 * 8];
            }
#pragma unroll
            for (int ni = 0; ni < 4; ++ni) {
                int row = wc * 64 + ni * 16 + l15;
                int idx8 = (kk * 4 + l4) ^ (row & 7);
                bfr[ni] = *(const bf16x8*)&lds[1][row * 64 + idx8 * 8];
            }
#pragma unroll
            for (int mi = 0; mi < 4; ++mi)
#pragma unroll
                for (int ni = 0; ni < 4; ++ni)
                    acc[mi][ni] = __builtin_amdgcn_mfma_f32_16x16x32_bf16(af[mi], bfr[ni], acc[mi][ni], 0, 0, 0);
        }
    };

    stage(0);
    asm volatile("s_waitcnt vmcnt(0)" ::: "memory");
    __syncthreads();
    for (int kt = 64; kt < K; kt += 64) {
        compute();
        __syncthreads();
        stage(kt);
        asm volatile("s_waitcnt vmcnt(0)" ::: "memory");
        __syncthreads();
    }
    compute();

    if (!Cf) {
        u16* st = &lds[0][0];            // [64][136]
#pragma unroll
        for (int p = 0; p < 2; ++p) {
            __syncthreads();
            if (wr == p) {
#pragma unroll
                for (int ni = 0; ni < 4; ++ni) {
                    int colL = wc * 64 + ni * 16 + l15;
                    float bv = bias ? bias[bn * 128 + colL] : 0.f;
#pragma unroll
                    for (int mi = 0; mi < 4; ++mi) {
#pragma unroll
                        for (int r = 0; r < 4; ++r) {
                            float v = acc[mi][ni][r] + bv;
                            if (doGelu) v = gelu_fast(v);
                            st[(mi * 16 + l4 * 4 + r) * 136 + colL] = f2b(v);
                        }
                    }
                }
            }
            __syncthreads();
            int lr = tid >> 2, q = tid & 3;
            const u16* src = st + lr * 136 + q * 32;
            u16* dst = C + (long long)(bm * 128 + p * 64 + lr) * N + bn * 128 + q * 32;
#pragma unroll
            for (int j = 0; j < 4; ++j)
                *(s16x8*)(dst + j * 8) = *(const s16x8*)(src + j * 8);
        }
    } else {
        float* stf = (float*)&lds[0][0];   // [32][132]
#pragma unroll
        for (int p = 0; p < 4; ++p) {
            __syncthreads();
            if (wc == (p >> 1)) {
#pragma unroll
                for (int nj = 0; nj < 2; ++nj) {
                    int ni = (p & 1) * 2 + nj;
                    int colL = wc * 64 + ni * 16 + l15;
                    int lc = nj * 16 + l15;
                    float bv = bias ? bias[bn * 128 + colL] : 0.f;
#pragma unroll
                    for (int mi = 0; mi < 4; ++mi) {
                        int row0 = wr * 64 + mi * 16 + l4 * 4;
#pragma unroll
                        for (int r = 0; r < 4; ++r) {
                            float v = acc[mi][ni][r] + bv
                                    + b2f(addT[(long long)(bm * 128 + row0 + r) * N + bn * 128 + colL]);
                            stf[lc * 132 + row0 + r] = v;
                        }
                    }
                }
            }
            __syncthreads();
            int lc = tid >> 3, q = tid & 7;
            float* dst = Cf + (long long)(bn * 128 + p * 32 + lc) * 4096 + bm * 128 + q * 16;
            const float* src = stf + lc * 132 + q * 16;
#pragma unroll
            for (int j = 0; j < 4; ++j)
                *(f32x4*)(dst + j * 4) = *(const f32x4*)(src + j * 4);
        }
    }
}

// ---------------- per-batch sum / sumsq partials over 1572864 f32 elems
__global__ __launch_bounds__(256)
void stats_part_kernel(const float* __restrict__ x, float* __restrict__ part)
{
    int b = blockIdx.x, cb = blockIdx.y, t = threadIdx.x;
    const float* p = x + (long long)b * PX + (long long)cb * 49152;
    float s = 0.f, q = 0.f;
    for (int i = 0; i < 48; ++i) {
        f32x4 v = *(const f32x4*)(p + (i * 256 + t) * 4);
#pragma unroll
        for (int j = 0; j < 4; ++j) { s += v[j]; q += v[j] * v[j]; }
    }
    for (int off = 32; off; off >>= 1) { s += __shfl_down(s, off); q += __shfl_down(q, off); }
    __shared__ float rs[4], rq[4];
    if ((t & 63) == 0) { rs[t >> 6] = s; rq[t >> 6] = q; }
    __syncthreads();
    if (t == 0) {
        part[(b * 32 + cb) * 2 + 0] = rs[0] + rs[1] + rs[2] + rs[3];
        part[(b * 32 + cb) * 2 + 1] = rq[0] + rq[1] + rq[2] + rq[3];
    }
}

__global__ void stats_fin_kernel(const float* __restrict__ part, float* __restrict__ mu, float* __restrict__ rsg)
{
    int b = blockIdx.x, l = threadIdx.x;
    float s = l < 32 ? part[(b * 32 + l) * 2 + 0] : 0.f;
    float q = l < 32 ? part[(b * 32 + l) * 2 + 1] : 0.f;
    for (int off = 32; off; off >>= 1) { s += __shfl_down(s, off); q += __shfl_down(q, off); }
    if (l == 0) {
        float m = s / 1572864.f;
        float v = q / 1572864.f - m * m; v = fmaxf(v, 0.f);
        mu[b] = m; rsg[b] = rsqrtf(v + 1e-5f);
    }
}

// ---------------- LN1 apply (f32 src, d-major) -> T-layout bf16
__global__ __launch_bounds__(256)
void ln_apply_T_kernel(const float* __restrict__ src, const float* __restrict__ w, const float* __restrict__ bb,
                       const float* __restrict__ mu, const float* __restrict__ rsg, u16* __restrict__ dstT)
{
    int nt = blockIdx.x, dt = blockIdx.y, b = blockIdx.z;
    int t = threadIdx.x, tx = t & 63, ty = t >> 6;
    __shared__ float tile[64][65];
    float m = mu[b], r = rsg[b];
    const long long base = (long long)b * PX;
#pragma unroll 4
    for (int i = 0; i < 16; ++i) {
        int dy = ty + i * 4;
        int d = dt * 64 + dy, n = nt * 64 + tx;
        long long widx = (long long)d * 4096 + n;
        tile[dy][tx] = (src[base + widx] - m) * r * w[widx] + bb[widx];
    }
    __syncthreads();
#pragma unroll 4
    for (int i = 0; i < 16; ++i) {
        int ny = ty + i * 4;
        int n = nt * 64 + ny, d = dt * 64 + tx;
        dstT[base + (long long)n * 384 + d] = f2b(tile[tx][ny]);
    }
}

// ---------------- row softmax over 768 contiguous channels (Q), in place
__global__ __launch_bounds__(256)
void softmax_rows_kernel(u16* __restrict__ QT)
{
    long long row = (long long)blockIdx.x * 4 + (threadIdx.x >> 6);
    int lane = threadIdx.x & 63;
    u16* p = QT + row * 768;
    float v[12];
#pragma unroll
    for (int g = 0; g < 3; ++g) {
        s16x4 a = *(const s16x4*)(p + g * 256 + lane * 4);
#pragma unroll
        for (int j = 0; j < 4; ++j) v[g * 4 + j] = b2f((u16)a[j]);
    }
    float m = -1e30f;
#pragma unroll
    for (int j = 0; j < 12; ++j) m = fmaxf(m, v[j]);
    for (int off = 32; off; off >>= 1) m = fmaxf(m, __shfl_xor(m, off));
    float s = 0.f;
#pragma unroll
    for (int j = 0; j < 12; ++j) { v[j] = __expf(v[j] - m); s += v[j]; }
    for (int off = 32; off; off >>= 1) s += __shfl_xor(s, off);
    float inv = 1.f / s;
#pragma unroll
    for (int g = 0; g < 3; ++g) {
        s16x4 o;
#pragma unroll
        for (int j = 0; j < 4; ++j) o[j] = (short)f2b(v[g * 4 + j] * inv);
        *(s16x4*)(p + g * 256 + lane * 4) = o;
    }
}

// ---------------- KV partials via MFMA, no-max exp (inputs bounded), CHUNK=128
__global__ __launch_bounds__(256)
void kv_part_kernel(const u16* __restrict__ KT, const u16* __restrict__ VT,
                    u16* __restrict__ KVp, float* __restrict__ sp)
{
    const int ch = blockIdx.x, h = blockIdx.y, b = blockIdx.z;
    const int t = threadIdx.x;
    const int lane = t & 63, w = t >> 6;

    __shared__ u16 kraw[128 * 64];
    __shared__ u16 eKT[64 * 128];
    __shared__ u16 Vt[32 * 128];
    __shared__ float reds[4][64];

    const u16* Kp = KT + (long long)b * PQ + (long long)(ch * 128) * 768 + h * 64;
    const u16* Vp = VT + (long long)b * PX + (long long)(ch * 128) * 384 + h * 32;

#pragma unroll
    for (int pass = 0; pass < 4; ++pass) {
        int cid = t + pass * 256;
        int row = cid >> 3, c8 = cid & 7;
        gl_lds16(Kp + (long long)row * 768 + c8 * 8, kraw + cid * 8);
    }

    {
        int v0 = (t & 7) * 4;
#pragma unroll
        for (int pass = 0; pass < 4; ++pass) {
            int n = (t >> 3) + pass * 32;
            s16x4 v4 = *(const s16x4*)(Vp + (long long)n * 384 + v0);
#pragma unroll
            for (int j = 0; j < 4; ++j) {
                int row = v0 + j;
                Vt[row * 128 + (n ^ ((row & 7) << 3))] = (u16)v4[j];
            }
        }
    }

    asm volatile("s_waitcnt vmcnt(0)" ::: "memory");
    __syncthreads();

    const int c = lane;
    {
        float s = 0.f;
        const int swz = (c & 7) << 3;
#pragma unroll
        for (int r8 = 0; r8 < 4; ++r8) {
            int rbase = w * 32 + r8 * 8;
            s16x8 buf;
#pragma unroll
            for (int j = 0; j < 8; ++j) {
                float e = __expf(b2f(kraw[(rbase + j) * 64 + c]));
                s += e;
                buf[j] = (short)f2b(e);
            }
            *(s16x8*)&eKT[c * 128 + (rbase ^ swz)] = buf;
        }
        reds[w][c] = s;
    }
    __syncthreads();

    if (t < 64)
        sp[((long long)(b * 12 + h) * 32 + ch) * 64 + t] =
            reds[0][t] + reds[1][t] + reds[2][t] + reds[3][t];

    const int l15 = lane & 15, l4 = lane >> 4;
    const int qrow = w * 16 + l15;
    const int sa = (qrow & 7) << 3;
    const int v0row = l15, v1row = 16 + l15;
    const int s0 = (v0row & 7) << 3, s1 = (v1row & 7) << 3;
    f32x4 acc0 = {}, acc1 = {};
#pragma unroll
    for (int ns = 0; ns < 4; ++ns) {
        int na = ns * 32 + l4 * 8;
        bf16x8 a  = *(const bf16x8*)&eKT[qrow * 128 + (na ^ sa)];
        bf16x8 b0 = *(const bf16x8*)&Vt[v0row * 128 + (na ^ s0)];
        bf16x8 b1 = *(const bf16x8*)&Vt[v1row * 128 + (na ^ s1)];
        acc0 = __builtin_amdgcn_mfma_f32_16x16x32_bf16(a, b0, acc0, 0, 0, 0);
        acc1 = __builtin_amdgcn_mfma_f32_16x16x32_bf16(a, b1, acc1, 0, 0, 0);
    }
    u16* Kb = KVp + ((long long)(b * 12 + h) * 32 + ch) * 2048;
#pragma unroll
    for (int r = 0; r < 4; ++r) {
        int q = w * 16 + l4 * 4 + r;
        Kb[q * 32 + l15]      = f2b(acc0[r]);
        Kb[q * 32 + 16 + l15] = f2b(acc1[r]);
    }
}

// ---------------- merge 32 KV partials -> WeffT (768 x 384 per batch)
__global__ __launch_bounds__(256)
void kv_fin_kernel(const u16* __restrict__ KVp, const float* __restrict__ sp,
                   u16* __restrict__ WeffT)
{
    const int h = blockIdx.x, b = blockIdx.y;
    const int t = threadIdx.x;
    __shared__ float fac[64];
    __shared__ float kvt[32][64];

    const long long pb = (long long)(b * 12 + h) * 32;
    if (t < 64) {
        float s = 0.f;
#pragma unroll
        for (int ch = 0; ch < 32; ++ch) s += sp[(pb + ch) * 64 + t];
        fac[t] = 1.f / (s * 4096.f);
    }
    __syncthreads();

    const int v0 = (t & 3) * 8, q = t >> 2;
    float acc[8] = {};
#pragma unroll
    for (int ch = 0; ch < 32; ++ch) {
        s16x8 kv8 = *(const s16x8*)&KVp[(pb + ch) * 2048 + q * 32 + v0];
#pragma unroll
        for (int j = 0; j < 8; ++j) acc[j] += b2f((u16)kv8[j]);
    }
    float fq = fac[q];
#pragma unroll
    for (int j = 0; j < 8; ++j) kvt[v0 + j][q] = acc[j] * fq;
    __syncthreads();

    u16* Wb = WeffT + (long long)b * 294912;
    for (int i = t; i < 64 * 384; i += 256) {
        int qq = i / 384, cc = i % 384;
        int cv = cc - h * 32;
        float val = (cv >= 0 && cv < 32) ? kvt[cv][qq] : 0.f;
        Wb[(long long)(h * 64 + qq) * 384 + cc] = f2b(val);
    }
}

// ---------------- transpose LN2 weight/bias (f32 d-major) -> bf16 T-layout
__global__ __launch_bounds__(256)
void wtrans_kernel(const float* __restrict__ w, const float* __restrict__ bb,
                   u16* __restrict__ wT, u16* __restrict__ bT)
{
    int nt = blockIdx.x, dt = blockIdx.y;
    const float* src = blockIdx.z ? bb : w;
    u16* dst = blockIdx.z ? bT : wT;
    int t = threadIdx.x, tx = t & 63, ty = t >> 6;
    __shared__ float tile[64][65];
#pragma unroll 4
    for (int i = 0; i < 16; ++i) {
        int dy = ty + i * 4;
        tile[dy][tx] = src[(long long)(dt * 64 + dy) * 4096 + nt * 64 + tx];
    }
    __syncthreads();
#pragma unroll 4
    for (int i = 0; i < 16; ++i) {
        int ny = ty + i * 4;
        dst[(long long)(nt * 64 + ny) * 384 + dt * 64 + tx] = f2b(tile[tx][ny]);
    }
}

// ---------------- residual 1: sT(T-layout bf16) = x^T + attnT, + LN2 partials
__global__ __launch_bounds__(256)
void resid1T_kernel(const float* __restrict__ x, const u16* __restrict__ attnT,
                    u16* __restrict__ sT, float* __restrict__ part2)
{
    int nt = blockIdx.x, dt = blockIdx.y, b = blockIdx.z;
    int t = threadIdx.x, tx = t & 63, ty = t >> 6;
    __shared__ float tile[64][65];
    const long long base = (long long)b * PX;
#pragma unroll 4
    for (int i = 0; i < 16; ++i) {
        int dy = ty + i * 4;
        tile[dy][tx] = x[base + (long long)(dt * 64 + dy) * 4096 + nt * 64 + tx];
    }
    __syncthreads();
    float ps = 0.f, pq = 0.f;
#pragma unroll 4
    for (int i = 0; i < 16; ++i) {
        int ny = ty + i * 4;
        long long idx = base + (long long)(nt * 64 + ny) * 384 + dt * 64 + tx;
        float val = tile[tx][ny] + b2f(attnT[idx]);
        sT[idx] = f2b(val);
        ps += val; pq += val * val;
    }
    for (int off = 32; off; off >>= 1) { ps += __shfl_down(ps, off); pq += __shfl_down(pq, off); }
    __shared__ float rs[4], rq[4];
    if ((t & 63) == 0) { rs[t >> 6] = ps; rq[t >> 6] = pq; }
    __syncthreads();
    if (t == 0) {
        int bid = (b * 6 + dt) * 64 + nt;
        part2[bid * 2 + 0] = rs[0] + rs[1] + rs[2] + rs[3];
        part2[bid * 2 + 1] = rq[0] + rq[1] + rq[2] + rq[3];
    }
}

__global__ __launch_bounds__(256)
void stats_fin2_kernel(const float* __restrict__ part2, float* __restrict__ mu, float* __restrict__ rsg)
{
    int b = blockIdx.x, t = threadIdx.x;
    float s = 0.f, q = 0.f;
    for (int i = t; i < 384; i += 256) { s += part2[(b * 384 + i) * 2]; q += part2[(b * 384 + i) * 2 + 1]; }
    for (int off = 32; off; off >>= 1) { s += __shfl_down(s, off); q += __shfl_down(q, off); }
    __shared__ float rs[4], rq[4];
    if ((t & 63) == 0) { rs[t >> 6] = s; rq[t >> 6] = q; }
    __syncthreads();
    if (t == 0) {
        float S = rs[0] + rs[1] + rs[2] + rs[3], Q = rq[0] + rq[1] + rq[2] + rq[3];
        float m = S / 1572864.f;
        float v = Q / 1572864.f - m * m; v = fmaxf(v, 0.f);
        mu[b] = m; rsg[b] = rsqrtf(v + 1e-5f);
    }
}

// ---------------- LN2 apply: elementwise T-layout, all bf16
__global__ __launch_bounds__(256)
void ln2_apply_kernel(const u16* __restrict__ sT, const u16* __restrict__ wT, const u16* __restrict__ bT,
                      const float* __restrict__ mu, const float* __restrict__ rsg, u16* __restrict__ x2T)
{
    int blk = blockIdx.x, b = blockIdx.y, t = threadIdx.x;
    float m = mu[b], r = rsg[b];
    long long wi = (long long)blk * 2048 + t * 8;
    long long gi = (long long)b * PX + wi;
    s16x8 sv = *(const s16x8*)(sT + gi);
    s16x8 wv = *(const s16x8*)(wT + wi);
    s16x8 bv = *(const s16x8*)(bT + wi);
    s16x8 o;
#pragma unroll
    for (int j = 0; j < 8; ++j)
        o[j] = (short)f2b((b2f((u16)sv[j]) - m) * r * b2f((u16)wv[j]) + b2f((u16)bv[j]));
    *(s16x8*)(x2T + gi) = o;
}

extern "C" void kernel_launch(void* const* d_in, const int* in_sizes, int n_in,
                              void* d_out, int out_size, void* d_ws, size_t ws_size,
                              hipStream_t stream)
{
    const float* x    = (const float*)d_in[0];
    const float* ln1w = (const float*)d_in[1];
    const float* ln1b = (const float*)d_in[2];
    const float* qw   = (const float*)d_in[3];
    const float* qb   = (const float*)d_in[4];
    const float* kw   = (const float*)d_in[5];
    const float* kb   = (const float*)d_in[6];
    const float* vw   = (const float*)d_in[7];
    const float* vb   = (const float*)d_in[8];
    const float* huw  = (const float*)d_in[9];
    const float* hub  = (const float*)d_in[10];
    const float* ln2w = (const float*)d_in[11];
    const float* ln2b = (const float*)d_in[12];
    const float* ff1w = (const float*)d_in[13];
    const float* ff1b = (const float*)d_in[14];
    const float* ff2w = (const float*)d_in[15];
    const float* ff2b = (const float*)d_in[16];
    float* out = (float*)d_out;

    char* ws = (char*)d_ws;
    u16*   aT    = (u16*)(ws + 0);                 //  50.3 MB region A
    u16*   QT    = (u16*)(ws + 50331648LL);        // 100.7 MB region B
    u16*   KT    = (u16*)(ws + 150994944LL);       // 100.7 MB region C
    u16*   VT    = (u16*)(ws + 251658240LL);       //  50.3 MB region D
    u16*   WeffT = (u16*)(ws + 301989888LL);       //   9.4 MB region E
    u16*   wcv   = (u16*)(ws + 311427072LL);       //   4.1 MB
    float* fbuf  = (float*)(ws + 315555840LL);     //  ~64 KB

    // region A overlays (aT dead after QKV GEMMs):
    u16*   KVp    = (u16*)(ws + 0);                // 25,165,824 B
    float* sp     = (float*)(ws + 25165824LL);     //  1,572,864 B
    u16*   WcombB = (u16*)(ws + 27525120LL);       //  9,437,184 B

    // region C overlays (KT dead after kv_part):
    u16* sT = KT;                                       // 50.3 MB
    u16* wT = (u16*)(ws + 150994944LL + 50331648LL);    //  3.1 MB
    u16* bT = (u16*)(ws + 150994944LL + 53477376LL);    //  3.1 MB
    u16* g8 = KT;                                       // 100.66 MB (after ln2_apply)

    u16* x2T   = QT;
    u16* attnT = VT;

    u16* qwB   = wcv;
    u16* kwB   = wcv + 294912;
    u16* vwB   = wcv + 589824;
    u16* huwB  = wcv + 737280;
    u16* ff1wB = wcv + 884736;
    u16* ff2wB = wcv + 1474560;

    float* part1 = fbuf;
    float* mu1   = fbuf + 1024;
    float* rs1   = fbuf + 1040;
    float* part2 = fbuf + 1056;
    float* mu2   = part2 + 12288;
    float* rs2   = mu2 + 16;

    wconv_kernel<<<2016, 256, 0, stream>>>(qw, kw, vw, huw, ff1w, ff2w, wcv);

    stats_part_kernel<<<dim3(16, 32), 256, 0, stream>>>(x, part1);
    stats_fin_kernel<<<16, 64, 0, stream>>>(part1, mu1, rs1);
    ln_apply_T_kernel<<<dim3(64, 6, 16), 256, 0, stream>>>(x, ln1w, ln1b, mu1, rs1, aT);

    // Q, K: wide 128x256 tiles (512 threads); V: 128x128
    gemm_wide_kernel<<<dim3(32, 3, 16), 512, 0, stream>>>(aT, PX, qwB, qb, QT, PQ, 384, 768, 0);
    gemm_wide_kernel<<<dim3(32, 3, 16), 512, 0, stream>>>(aT, PX, kwB, kb, KT, PQ, 384, 768, 0);
    gemm_bt_kernel<<<dim3(32, 3, 16), 256, 0, stream>>>(aT, PX, vwB, 0, vb, VT, PX, nullptr, nullptr, 0, 384, 384, 0);

    softmax_rows_kernel<<<16384, 256, 0, stream>>>(QT);

    kv_part_kernel<<<dim3(32, 12, 16), 256, 0, stream>>>(KT, VT, KVp, sp);
    kv_fin_kernel<<<dim3(12, 16), 256, 0, stream>>>(KVp, sp, WeffT);

    wtrans_kernel<<<dim3(64, 6, 2), 256, 0, stream>>>(ln2w, ln2b, wT, bT);

    gemm_bt_kernel<<<dim3(3, 6, 16), 256, 0, stream>>>(huwB, 0, WeffT, 294912, nullptr, WcombB, 294912, nullptr, nullptr, 0, 384, 768, 0);

    gemm_bt_kernel<<<dim3(32, 3, 16), 256, 0, stream>>>(QT, PQ, WcombB, 294912, hub, attnT, PX, nullptr, nullptr, 0, 768, 384, 0);

    resid1T_kernel<<<dim3(64, 6, 16), 256, 0, stream>>>(x, attnT, sT, part2);
    stats_fin2_kernel<<<16, 256, 0, stream>>>(part2, mu2, rs2);
    ln2_apply_kernel<<<dim3(768, 16), 256, 0, stream>>>(sT, wT, bT, mu2, rs2, x2T);

    // FFN in 2 chunks of 8 batches; FF1 wide (N=1536), FF2 128x128 f32-out
    for (int c = 0; c < 2; ++c) {
        gemm_wide_kernel<<<dim3(32, 6, 8), 512, 0, stream>>>(
            x2T + (long long)c * 8 * PX, PX, ff1wB, ff1b,
            g8, PH, 384, 1536, 1);
        gemm_bt_kernel<<<dim3(32, 3, 8), 256, 0, stream>>>(
            g8, PH, ff2wB, 0, ff2b,
            nullptr, PX, out + (long long)c * 8 * PX,
            x2T + (long long)c * 8 * PX, PX, 1536, 384, 0);
    }
}

// Round 18
// 759.423 us; speedup vs baseline: 2.0232x; 1.0631x over previous
//
#include <hip/hip_runtime.h>
#include <hip/hip_bf16.h>

using u16 = unsigned short;
typedef __attribute__((ext_vector_type(4))) float f32x4;
typedef __bf16 bf16x8 __attribute__((ext_vector_type(8)));
typedef short s16x4 __attribute__((ext_vector_type(4)));
typedef short s16x8 __attribute__((ext_vector_type(8)));

#define DEVI __device__ __forceinline__

DEVI float b2f(u16 u) {
    union { unsigned i; float f; } x; x.i = ((unsigned)u) << 16; return x.f;
}
DEVI u16 f2b(float f) {
    union { float f; unsigned i; } x; x.f = f;
    unsigned r = (x.i + 0x7fffu + ((x.i >> 16) & 1u)) >> 16;
    return (u16)r;
}

// fast gelu: v * sigmoid(1.5957691 v + 0.0713548 v^3)  (tanh-form, overflow-safe)
DEVI float gelu_fast(float v) {
    float t = v * (1.5957691f + 0.0713548162f * v * v);
    return v / (1.f + __expf(-t));
}

static constexpr long long PX = 1572864LL;  // 384*4096 per batch
static constexpr long long PQ = 3145728LL;  // 768*4096 per batch
static constexpr long long PH = 6291456LL;  // 1536*4096 per batch

DEVI void gl_lds16(const u16* g, u16* l) {
    __builtin_amdgcn_global_load_lds(
        (const __attribute__((address_space(1))) unsigned int*)g,
        (__attribute__((address_space(3))) unsigned int*)l, 16, 0, 0);
}

// ---------------- all weight f32 -> bf16 conversions in ONE launch
__global__ __launch_bounds__(256)
void wconv_kernel(const float* __restrict__ qw, const float* __restrict__ kw,
                  const float* __restrict__ vw, const float* __restrict__ huw,
                  const float* __restrict__ ff1w, const float* __restrict__ ff2w,
                  u16* __restrict__ wcv)
{
    int blk = blockIdx.x;
    const float* src; u16* dst; int lb;
    if      (blk < 288)  { src = qw;   dst = wcv;           lb = blk; }
    else if (blk < 576)  { src = kw;   dst = wcv + 294912;  lb = blk - 288; }
    else if (blk < 720)  { src = vw;   dst = wcv + 589824;  lb = blk - 576; }
    else if (blk < 864)  { src = huw;  dst = wcv + 737280;  lb = blk - 720; }
    else if (blk < 1440) { src = ff1w; dst = wcv + 884736;  lb = blk - 864; }
    else                 { src = ff2w; dst = wcv + 1474560; lb = blk - 1440; }
    int i = (lb * 256 + threadIdx.x) * 4;
    f32x4 v = *(const f32x4*)(src + i);
    s16x4 o;
#pragma unroll
    for (int j = 0; j < 4; ++j) o[j] = (short)f2b(v[j]);
    *(s16x4*)(dst + i) = o;
}

// ---------------- concat q/k/v biases into one 1920-float buffer
__global__ __launch_bounds__(256)
void bcat_kernel(const float* __restrict__ qb, const float* __restrict__ kb,
                 const float* __restrict__ vb, float* __restrict__ o)
{
    int i = blockIdx.x * 256 + threadIdx.x;
    if (i < 768)       o[i] = qb[i];
    else if (i < 1536) o[i] = kb[i - 768];
    else if (i < 1920) o[i] = vb[i - 1536];
}

// ---------------- fused QKV GEMM: one dispatch over N=1920 (=768Q|768K|384V)
// Identical main loop to gemm_bt (proven R10/R14 structure); epilogue routes
// each bn-tile to QT / KT / VT. Weights contiguous in wcv; bias concat.
__global__ __launch_bounds__(256, 4)
void gemm_qkv_kernel(const u16* __restrict__ A, long long strideA,
                     const u16* __restrict__ Bw,
                     const float* __restrict__ bias,
                     u16* __restrict__ Q, u16* __restrict__ Kd, u16* __restrict__ V,
                     int K)
{
    const int tid = threadIdx.x;
    const int lane = tid & 63;
    const int wv = tid >> 6;
    const int wr = wv >> 1, wc = wv & 1;
    const int l15 = lane & 15, l4 = lane >> 4;
    const int bm = blockIdx.x, bn = blockIdx.y, bz = blockIdx.z;

    A += (long long)bz * strideA;
    u16* dstBase; int Nout; int colBase;
    if (bn < 6)       { dstBase = Q  + (long long)bz * PQ; Nout = 768; colBase = bn * 128; }
    else if (bn < 12) { dstBase = Kd + (long long)bz * PQ; Nout = 768; colBase = (bn - 6) * 128; }
    else              { dstBase = V  + (long long)bz * PX; Nout = 384; colBase = (bn - 12) * 128; }

    __shared__ u16 lds[2][128 * 64];   // 32 KB

    f32x4 acc[4][4] = {};

    auto stage = [&](int kt) {
#pragma unroll
        for (int i = 0; i < 4; ++i) {
            int cid = tid + i * 256;
            int row = cid >> 3, c8 = cid & 7;
            int c8s = c8 ^ (row & 7);
            gl_lds16(A + (long long)(bm * 128 + row) * K + kt + c8s * 8,
                     &lds[0][cid * 8]);
        }
#pragma unroll
        for (int i = 0; i < 4; ++i) {
            int cid = tid + i * 256;
            int row = cid >> 3, c8 = cid & 7;
            int c8s = c8 ^ (row & 7);
            gl_lds16(Bw + (long long)(bn * 128 + row) * K + kt + c8s * 8,
                     &lds[1][cid * 8]);
        }
    };

    auto compute = [&]() {
#pragma unroll
        for (int kk = 0; kk < 2; ++kk) {
            bf16x8 af[4], bfr[4];
#pragma unroll
            for (int mi = 0; mi < 4; ++mi) {
                int row = wr * 64 + mi * 16 + l15;
                int idx8 = (kk * 4 + l4) ^ (row & 7);
                af[mi] = *(const bf16x8*)&lds[0][row * 64 + idx8 * 8];
            }
#pragma unroll
            for (int ni = 0; ni < 4; ++ni) {
                int row = wc * 64 + ni * 16 + l15;
                int idx8 = (kk * 4 + l4) ^ (row & 7);
                bfr[ni] = *(const bf16x8*)&lds[1][row * 64 + idx8 * 8];
            }
#pragma unroll
            for (int mi = 0; mi < 4; ++mi)
#pragma unroll
                for (int ni = 0; ni < 4; ++ni)
                    acc[mi][ni] = __builtin_amdgcn_mfma_f32_16x16x32_bf16(af[mi], bfr[ni], acc[mi][ni], 0, 0, 0);
        }
    };

    stage(0);
    asm volatile("s_waitcnt vmcnt(0)" ::: "memory");
    __syncthreads();
    for (int kt = 64; kt < K; kt += 64) {
        compute();
        __syncthreads();
        stage(kt);
        asm volatile("s_waitcnt vmcnt(0)" ::: "memory");
        __syncthreads();
    }
    compute();

    u16* st = &lds[0][0];            // [64][136]
#pragma unroll
    for (int p = 0; p < 2; ++p) {
        __syncthreads();
        if (wr == p) {
#pragma unroll
            for (int ni = 0; ni < 4; ++ni) {
                int colL = wc * 64 + ni * 16 + l15;
                float bv = bias[bn * 128 + colL];
#pragma unroll
                for (int mi = 0; mi < 4; ++mi) {
#pragma unroll
                    for (int r = 0; r < 4; ++r)
                        st[(mi * 16 + l4 * 4 + r) * 136 + colL] = f2b(acc[mi][ni][r] + bv);
                }
            }
        }
        __syncthreads();
        int lr = tid >> 2, q = tid & 3;
        const u16* src = st + lr * 136 + q * 32;
        u16* dst = dstBase + (long long)(bm * 128 + p * 64 + lr) * Nout + colBase + q * 32;
#pragma unroll
        for (int j = 0; j < 4; ++j)
            *(s16x8*)(dst + j * 8) = *(const s16x8*)(src + j * 8);
    }
}

// ---------------- GEMM 128x128 (R10 structure), bf16 or f32-dmajor epilogue
__global__ __launch_bounds__(256, 4)
void gemm_bt_kernel(const u16* __restrict__ A, long long strideA,
                    const u16* __restrict__ Bw, long long strideB,
                    const float* __restrict__ bias,
                    u16* __restrict__ C, long long strideC,
                    float* __restrict__ Cf,
                    const u16* __restrict__ addT, long long strideAdd,
                    int K, int N, int doGelu)
{
    const int tid = threadIdx.x;
    const int lane = tid & 63;
    const int wv = tid >> 6;
    const int wr = wv >> 1, wc = wv & 1;
    const int l15 = lane & 15, l4 = lane >> 4;
    const int bm = blockIdx.x, bn = blockIdx.y, bz = blockIdx.z;

    A  += (long long)bz * strideA;
    Bw += (long long)bz * strideB;
    if (C)    C    += (long long)bz * strideC;
    if (Cf)   Cf   += (long long)bz * strideC;
    if (addT) addT += (long long)bz * strideAdd;

    __shared__ u16 lds[2][128 * 64];   // 32 KB

    f32x4 acc[4][4] = {};

    auto stage = [&](int kt) {
#pragma unroll
        for (int i = 0; i < 4; ++i) {
            int cid = tid + i * 256;
            int row = cid >> 3, c8 = cid & 7;
            int c8s = c8 ^ (row & 7);
            gl_lds16(A + (long long)(bm * 128 + row) * K + kt + c8s * 8,
                     &lds[0][cid * 8]);
        }
#pragma unroll
        for (int i = 0; i < 4; ++i) {
            int cid = tid + i * 256;
            int row = cid >> 3, c8 = cid & 7;
            int c8s = c8 ^ (row & 7);
            gl_lds16(Bw + (long long)(bn * 128 + row) * K + kt + c8s * 8,
                     &lds[1][cid * 8]);
        }
    };

    auto compute = [&]() {
#pragma unroll
        for (int kk = 0; kk < 2; ++kk) {
            bf16x8 af[4], bfr[4];
#pragma unroll
            for (int mi = 0; mi < 4; ++mi) {
                int row = wr * 64 + mi * 16 + l15;
                int idx8 = (kk * 4 + l4) ^ (row & 7);
                af[mi] = *(const bf16x8*)&lds[0][row * 64 + idx8 * 8];
            }
#pragma unroll
            for (int ni = 0; ni < 4; ++ni) {
                int row = wc * 64 + ni * 16 + l15;
                int idx8 = (kk * 4 + l4) ^ (row & 7);
                bfr[ni] = *(const bf16x8*)&lds[1][row * 64 + idx8 * 8];
            }
#pragma unroll
            for (int mi = 0; mi < 4; ++mi)
#pragma unroll
                for (int ni = 0; ni < 4; ++ni)
                    acc[mi][ni] = __builtin_amdgcn_mfma_f32_16x16x32_bf16(af[mi], bfr[ni], acc[mi][ni], 0, 0, 0);
        }
    };

    stage(0);
    asm volatile("s_waitcnt vmcnt(0)" ::: "memory");
    __syncthreads();
    for (int kt = 64; kt < K; kt += 64) {
        compute();
        __syncthreads();
        stage(kt);
        asm volatile("s_waitcnt vmcnt(0)" ::: "memory");
        __syncthreads();
    }
    compute();

    if (!Cf) {
        u16* st = &lds[0][0];            // [64][136]
#pragma unroll
        for (int p = 0; p < 2; ++p) {
            __syncthreads();
            if (wr == p) {
#pragma unroll
                for (int ni = 0; ni < 4; ++ni) {
                    int colL = wc * 64 + ni * 16 + l15;
                    float bv = bias ? bias[bn * 128 + colL] : 0.f;
#pragma unroll
                    for (int mi = 0; mi < 4; ++mi) {
#pragma unroll
                        for (int r = 0; r < 4; ++r) {
                            float v = acc[mi][ni][r] + bv;
                            if (doGelu) v = gelu_fast(v);
                            st[(mi * 16 + l4 * 4 + r) * 136 + colL] = f2b(v);
                        }
                    }
                }
            }
            __syncthreads();
            int lr = tid >> 2, q = tid & 3;
            const u16* src = st + lr * 136 + q * 32;
            u16* dst = C + (long long)(bm * 128 + p * 64 + lr) * N + bn * 128 + q * 32;
#pragma unroll
            for (int j = 0; j < 4; ++j)
                *(s16x8*)(dst + j * 8) = *(const s16x8*)(src + j * 8);
        }
    } else {
        float* stf = (float*)&lds[0][0];   // [32][132]
#pragma unroll
        for (int p = 0; p < 4; ++p) {
            __syncthreads();
            if (wc == (p >> 1)) {
#pragma unroll
                for (int nj = 0; nj < 2; ++nj) {
                    int ni = (p & 1) * 2 + nj;
                    int colL = wc * 64 + ni * 16 + l15;
                    int lc = nj * 16 + l15;
                    float bv = bias ? bias[bn * 128 + colL] : 0.f;
#pragma unroll
                    for (int mi = 0; mi < 4; ++mi) {
                        int row0 = wr * 64 + mi * 16 + l4 * 4;
#pragma unroll
                        for (int r = 0; r < 4; ++r) {
                            float v = acc[mi][ni][r] + bv
                                    + b2f(addT[(long long)(bm * 128 + row0 + r) * N + bn * 128 + colL]);
                            stf[lc * 132 + row0 + r] = v;
                        }
                    }
                }
            }
            __syncthreads();
            int lc = tid >> 3, q = tid & 7;
            float* dst = Cf + (long long)(bn * 128 + p * 32 + lc) * 4096 + bm * 128 + q * 16;
            const float* src = stf + lc * 132 + q * 16;
#pragma unroll
            for (int j = 0; j < 4; ++j)
                *(f32x4*)(dst + j * 4) = *(const f32x4*)(src + j * 4);
        }
    }
}

// ---------------- per-batch sum / sumsq partials over 1572864 f32 elems
__global__ __launch_bounds__(256)
void stats_part_kernel(const float* __restrict__ x, float* __restrict__ part)
{
    int b = blockIdx.x, cb = blockIdx.y, t = threadIdx.x;
    const float* p = x + (long long)b * PX + (long long)cb * 49152;
    float s = 0.f, q = 0.f;
    for (int i = 0; i < 48; ++i) {
        f32x4 v = *(const f32x4*)(p + (i * 256 + t) * 4);
#pragma unroll
        for (int j = 0; j < 4; ++j) { s += v[j]; q += v[j] * v[j]; }
    }
    for (int off = 32; off; off >>= 1) { s += __shfl_down(s, off); q += __shfl_down(q, off); }
    __shared__ float rs[4], rq[4];
    if ((t & 63) == 0) { rs[t >> 6] = s; rq[t >> 6] = q; }
    __syncthreads();
    if (t == 0) {
        part[(b * 32 + cb) * 2 + 0] = rs[0] + rs[1] + rs[2] + rs[3];
        part[(b * 32 + cb) * 2 + 1] = rq[0] + rq[1] + rq[2] + rq[3];
    }
}

__global__ void stats_fin_kernel(const float* __restrict__ part, float* __restrict__ mu, float* __restrict__ rsg)
{
    int b = blockIdx.x, l = threadIdx.x;
    float s = l < 32 ? part[(b * 32 + l) * 2 + 0] : 0.f;
    float q = l < 32 ? part[(b * 32 + l) * 2 + 1] : 0.f;
    for (int off = 32; off; off >>= 1) { s += __shfl_down(s, off); q += __shfl_down(q, off); }
    if (l == 0) {
        float m = s / 1572864.f;
        float v = q / 1572864.f - m * m; v = fmaxf(v, 0.f);
        mu[b] = m; rsg[b] = rsqrtf(v + 1e-5f);
    }
}

// ---------------- LN1 apply (f32 src, d-major) -> T-layout bf16
__global__ __launch_bounds__(256)
void ln_apply_T_kernel(const float* __restrict__ src, const float* __restrict__ w, const float* __restrict__ bb,
                       const float* __restrict__ mu, const float* __restrict__ rsg, u16* __restrict__ dstT)
{
    int nt = blockIdx.x, dt = blockIdx.y, b = blockIdx.z;
    int t = threadIdx.x, tx = t & 63, ty = t >> 6;
    __shared__ float tile[64][65];
    float m = mu[b], r = rsg[b];
    const long long base = (long long)b * PX;
#pragma unroll 4
    for (int i = 0; i < 16; ++i) {
        int dy = ty + i * 4;
        int d = dt * 64 + dy, n = nt * 64 + tx;
        long long widx = (long long)d * 4096 + n;
        tile[dy][tx] = (src[base + widx] - m) * r * w[widx] + bb[widx];
    }
    __syncthreads();
#pragma unroll 4
    for (int i = 0; i < 16; ++i) {
        int ny = ty + i * 4;
        int n = nt * 64 + ny, d = dt * 64 + tx;
        dstT[base + (long long)n * 384 + d] = f2b(tile[tx][ny]);
    }
}

// ---------------- row softmax over 768 contiguous channels (Q), in place
__global__ __launch_bounds__(256)
void softmax_rows_kernel(u16* __restrict__ QT)
{
    long long row = (long long)blockIdx.x * 4 + (threadIdx.x >> 6);
    int lane = threadIdx.x & 63;
    u16* p = QT + row * 768;
    float v[12];
#pragma unroll
    for (int g = 0; g < 3; ++g) {
        s16x4 a = *(const s16x4*)(p + g * 256 + lane * 4);
#pragma unroll
        for (int j = 0; j < 4; ++j) v[g * 4 + j] = b2f((u16)a[j]);
    }
    float m = -1e30f;
#pragma unroll
    for (int j = 0; j < 12; ++j) m = fmaxf(m, v[j]);
    for (int off = 32; off; off >>= 1) m = fmaxf(m, __shfl_xor(m, off));
    float s = 0.f;
#pragma unroll
    for (int j = 0; j < 12; ++j) { v[j] = __expf(v[j] - m); s += v[j]; }
    for (int off = 32; off; off >>= 1) s += __shfl_xor(s, off);
    float inv = 1.f / s;
#pragma unroll
    for (int g = 0; g < 3; ++g) {
        s16x4 o;
#pragma unroll
        for (int j = 0; j < 4; ++j) o[j] = (short)f2b(v[g * 4 + j] * inv);
        *(s16x4*)(p + g * 256 + lane * 4) = o;
    }
}

// ---------------- KV partials via MFMA, no-max exp (inputs bounded), CHUNK=128
__global__ __launch_bounds__(256)
void kv_part_kernel(const u16* __restrict__ KT, const u16* __restrict__ VT,
                    u16* __restrict__ KVp, float* __restrict__ sp)
{
    const int ch = blockIdx.x, h = blockIdx.y, b = blockIdx.z;
    const int t = threadIdx.x;
    const int lane = t & 63, w = t >> 6;

    __shared__ u16 kraw[128 * 64];
    __shared__ u16 eKT[64 * 128];
    __shared__ u16 Vt[32 * 128];
    __shared__ float reds[4][64];

    const u16* Kp = KT + (long long)b * PQ + (long long)(ch * 128) * 768 + h * 64;
    const u16* Vp = VT + (long long)b * PX + (long long)(ch * 128) * 384 + h * 32;

#pragma unroll
    for (int pass = 0; pass < 4; ++pass) {
        int cid = t + pass * 256;
        int row = cid >> 3, c8 = cid & 7;
        gl_lds16(Kp + (long long)row * 768 + c8 * 8, kraw + cid * 8);
    }

    {
        int v0 = (t & 7) * 4;
#pragma unroll
        for (int pass = 0; pass < 4; ++pass) {
            int n = (t >> 3) + pass * 32;
            s16x4 v4 = *(const s16x4*)(Vp + (long long)n * 384 + v0);
#pragma unroll
            for (int j = 0; j < 4; ++j) {
                int row = v0 + j;
                Vt[row * 128 + (n ^ ((row & 7) << 3))] = (u16)v4[j];
            }
        }
    }

    asm volatile("s_waitcnt vmcnt(0)" ::: "memory");
    __syncthreads();

    const int c = lane;
    {
        float s = 0.f;
        const int swz = (c & 7) << 3;
#pragma unroll
        for (int r8 = 0; r8 < 4; ++r8) {
            int rbase = w * 32 + r8 * 8;
            s16x8 buf;
#pragma unroll
            for (int j = 0; j < 8; ++j) {
                float e = __expf(b2f(kraw[(rbase + j) * 64 + c]));
                s += e;
                buf[j] = (short)f2b(e);
            }
            *(s16x8*)&eKT[c * 128 + (rbase ^ swz)] = buf;
        }
        reds[w][c] = s;
    }
    __syncthreads();

    if (t < 64)
        sp[((long long)(b * 12 + h) * 32 + ch) * 64 + t] =
            reds[0][t] + reds[1][t] + reds[2][t] + reds[3][t];

    const int l15 = lane & 15, l4 = lane >> 4;
    const int qrow = w * 16 + l15;
    const int sa = (qrow & 7) << 3;
    const int v0row = l15, v1row = 16 + l15;
    const int s0 = (v0row & 7) << 3, s1 = (v1row & 7) << 3;
    f32x4 acc0 = {}, acc1 = {};
#pragma unroll
    for (int ns = 0; ns < 4; ++ns) {
        int na = ns * 32 + l4 * 8;
        bf16x8 a  = *(const bf16x8*)&eKT[qrow * 128 + (na ^ sa)];
        bf16x8 b0 = *(const bf16x8*)&Vt[v0row * 128 + (na ^ s0)];
        bf16x8 b1 = *(const bf16x8*)&Vt[v1row * 128 + (na ^ s1)];
        acc0 = __builtin_amdgcn_mfma_f32_16x16x32_bf16(a, b0, acc0, 0, 0, 0);
        acc1 = __builtin_amdgcn_mfma_f32_16x16x32_bf16(a, b1, acc1, 0, 0, 0);
    }
    u16* Kb = KVp + ((long long)(b * 12 + h) * 32 + ch) * 2048;
#pragma unroll
    for (int r = 0; r < 4; ++r) {
        int q = w * 16 + l4 * 4 + r;
        Kb[q * 32 + l15]      = f2b(acc0[r]);
        Kb[q * 32 + 16 + l15] = f2b(acc1[r]);
    }
}

// ---------------- merge 32 KV partials -> WeffT (768 x 384 per batch)
__global__ __launch_bounds__(256)
void kv_fin_kernel(const u16* __restrict__ KVp, const float* __restrict__ sp,
                   u16* __restrict__ WeffT)
{
    const int h = blockIdx.x, b = blockIdx.y;
    const int t = threadIdx.x;
    __shared__ float fac[64];
    __shared__ float kvt[32][64];

    const long long pb = (long long)(b * 12 + h) * 32;
    if (t < 64) {
        float s = 0.f;
#pragma unroll
        for (int ch = 0; ch < 32; ++ch) s += sp[(pb + ch) * 64 + t];
        fac[t] = 1.f / (s * 4096.f);
    }
    __syncthreads();

    const int v0 = (t & 3) * 8, q = t >> 2;
    float acc[8] = {};
#pragma unroll
    for (int ch = 0; ch < 32; ++ch) {
        s16x8 kv8 = *(const s16x8*)&KVp[(pb + ch) * 2048 + q * 32 + v0];
#pragma unroll
        for (int j = 0; j < 8; ++j) acc[j] += b2f((u16)kv8[j]);
    }
    float fq = fac[q];
#pragma unroll
    for (int j = 0; j < 8; ++j) kvt[v0 + j][q] = acc[j] * fq;
    __syncthreads();

    u16* Wb = WeffT + (long long)b * 294912;
    for (int i = t; i < 64 * 384; i += 256) {
        int qq = i / 384, cc = i % 384;
        int cv = cc - h * 32;
        float val = (cv >= 0 && cv < 32) ? kvt[cv][qq] : 0.f;
        Wb[(long long)(h * 64 + qq) * 384 + cc] = f2b(val);
    }
}

// ---------------- transpose LN2 weight/bias (f32 d-major) -> bf16 T-layout
__global__ __launch_bounds__(256)
void wtrans_kernel(const float* __restrict__ w, const float* __restrict__ bb,
                   u16* __restrict__ wT, u16* __restrict__ bT)
{
    int nt = blockIdx.x, dt = blockIdx.y;
    const float* src = blockIdx.z ? bb : w;
    u16* dst = blockIdx.z ? bT : wT;
    int t = threadIdx.x, tx = t & 63, ty = t >> 6;
    __shared__ float tile[64][65];
#pragma unroll 4
    for (int i = 0; i < 16; ++i) {
        int dy = ty + i * 4;
        tile[dy][tx] = src[(long long)(dt * 64 + dy) * 4096 + nt * 64 + tx];
    }
    __syncthreads();
#pragma unroll 4
    for (int i = 0; i < 16; ++i) {
        int ny = ty + i * 4;
        dst[(long long)(nt * 64 + ny) * 384 + dt * 64 + tx] = f2b(tile[tx][ny]);
    }
}

// ---------------- residual 1: sT(T-layout bf16) = x^T + attnT, + LN2 partials
__global__ __launch_bounds__(256)
void resid1T_kernel(const float* __restrict__ x, const u16* __restrict__ attnT,
                    u16* __restrict__ sT, float* __restrict__ part2)
{
    int nt = blockIdx.x, dt = blockIdx.y, b = blockIdx.z;
    int t = threadIdx.x, tx = t & 63, ty = t >> 6;
    __shared__ float tile[64][65];
    const long long base = (long long)b * PX;
#pragma unroll 4
    for (int i = 0; i < 16; ++i) {
        int dy = ty + i * 4;
        tile[dy][tx] = x[base + (long long)(dt * 64 + dy) * 4096 + nt * 64 + tx];
    }
    __syncthreads();
    float ps = 0.f, pq = 0.f;
#pragma unroll 4
    for (int i = 0; i < 16; ++i) {
        int ny = ty + i * 4;
        long long idx = base + (long long)(nt * 64 + ny) * 384 + dt * 64 + tx;
        float val = tile[tx][ny] + b2f(attnT[idx]);
        sT[idx] = f2b(val);
        ps += val; pq += val * val;
    }
    for (int off = 32; off; off >>= 1) { ps += __shfl_down(ps, off); pq += __shfl_down(pq, off); }
    __shared__ float rs[4], rq[4];
    if ((t & 63) == 0) { rs[t >> 6] = ps; rq[t >> 6] = pq; }
    __syncthreads();
    if (t == 0) {
        int bid = (b * 6 + dt) * 64 + nt;
        part2[bid * 2 + 0] = rs[0] + rs[1] + rs[2] + rs[3];
        part2[bid * 2 + 1] = rq[0] + rq[1] + rq[2] + rq[3];
    }
}

__global__ __launch_bounds__(256)
void stats_fin2_kernel(const float* __restrict__ part2, float* __restrict__ mu, float* __restrict__ rsg)
{
    int b = blockIdx.x, t = threadIdx.x;
    float s = 0.f, q = 0.f;
    for (int i = t; i < 384; i += 256) { s += part2[(b * 384 + i) * 2]; q += part2[(b * 384 + i) * 2 + 1]; }
    for (int off = 32; off; off >>= 1) { s += __shfl_down(s, off); q += __shfl_down(q, off); }
    __shared__ float rs[4], rq[4];
    if ((t & 63) == 0) { rs[t >> 6] = s; rq[t >> 6] = q; }
    __syncthreads();
    if (t == 0) {
        float S = rs[0] + rs[1] + rs[2] + rs[3], Q = rq[0] + rq[1] + rq[2] + rq[3];
        float m = S / 1572864.f;
        float v = Q / 1572864.f - m * m; v = fmaxf(v, 0.f);
        mu[b] = m; rsg[b] = rsqrtf(v + 1e-5f);
    }
}

// ---------------- LN2 apply: elementwise T-layout, all bf16
__global__ __launch_bounds__(256)
void ln2_apply_kernel(const u16* __restrict__ sT, const u16* __restrict__ wT, const u16* __restrict__ bT,
                      const float* __restrict__ mu, const float* __restrict__ rsg, u16* __restrict__ x2T)
{
    int blk = blockIdx.x, b = blockIdx.y, t = threadIdx.x;
    float m = mu[b], r = rsg[b];
    long long wi = (long long)blk * 2048 + t * 8;
    long long gi = (long long)b * PX + wi;
    s16x8 sv = *(const s16x8*)(sT + gi);
    s16x8 wv = *(const s16x8*)(wT + wi);
    s16x8 bv = *(const s16x8*)(bT + wi);
    s16x8 o;
#pragma unroll
    for (int j = 0; j < 8; ++j)
        o[j] = (short)f2b((b2f((u16)sv[j]) - m) * r * b2f((u16)wv[j]) + b2f((u16)bv[j]));
    *(s16x8*)(x2T + gi) = o;
}

extern "C" void kernel_launch(void* const* d_in, const int* in_sizes, int n_in,
                              void* d_out, int out_size, void* d_ws, size_t ws_size,
                              hipStream_t stream)
{
    const float* x    = (const float*)d_in[0];
    const float* ln1w = (const float*)d_in[1];
    const float* ln1b = (const float*)d_in[2];
    const float* qw   = (const float*)d_in[3];
    const float* qb   = (const float*)d_in[4];
    const float* kw   = (const float*)d_in[5];
    const float* kb   = (const float*)d_in[6];
    const float* vw   = (const float*)d_in[7];
    const float* vb   = (const float*)d_in[8];
    const float* huw  = (const float*)d_in[9];
    const float* hub  = (const float*)d_in[10];
    const float* ln2w = (const float*)d_in[11];
    const float* ln2b = (const float*)d_in[12];
    const float* ff1w = (const float*)d_in[13];
    const float* ff1b = (const float*)d_in[14];
    const float* ff2w = (const float*)d_in[15];
    const float* ff2b = (const float*)d_in[16];
    float* out = (float*)d_out;

    char* ws = (char*)d_ws;
    u16*   aT    = (u16*)(ws + 0);                 //  50.3 MB region A
    u16*   QT    = (u16*)(ws + 50331648LL);        // 100.7 MB region B
    u16*   KT    = (u16*)(ws + 150994944LL);       // 100.7 MB region C
    u16*   VT    = (u16*)(ws + 251658240LL);       //  50.3 MB region D
    u16*   WeffT = (u16*)(ws + 301989888LL);       //   9.4 MB region E
    u16*   wcv   = (u16*)(ws + 311427072LL);       //   4.1 MB
    float* fbuf  = (float*)(ws + 315555840LL);     //  ~64 KB

    // region A overlays (aT dead after QKV GEMM):
    u16*   KVp    = (u16*)(ws + 0);                // 25,165,824 B
    float* sp     = (float*)(ws + 25165824LL);     //  1,572,864 B
    u16*   WcombB = (u16*)(ws + 27525120LL);       //  9,437,184 B

    // region C overlays (KT dead after kv_part):
    u16* sT = KT;                                       // 50.3 MB
    u16* wT = (u16*)(ws + 150994944LL + 50331648LL);    //  3.1 MB
    u16* bT = (u16*)(ws + 150994944LL + 53477376LL);    //  3.1 MB
    u16* g8 = KT;                                       // 100.66 MB (after ln2_apply)

    u16* x2T   = QT;
    u16* attnT = VT;

    u16* qwB   = wcv;        // rows 0..767   of the fused 1920x384 weight
    u16* ff1wB = wcv + 884736;
    u16* ff2wB = wcv + 1474560;
    u16* huwB  = wcv + 737280;

    float* part1 = fbuf;               // 1024
    float* mu1   = fbuf + 1024;        // 16
    float* rs1   = fbuf + 1040;        // 16
    float* part2 = fbuf + 1056;        // 12288
    float* mu2   = part2 + 12288;      // 16
    float* rs2   = mu2 + 16;           // 16
    float* qkvb  = rs2 + 16;           // 1920

    wconv_kernel<<<2016, 256, 0, stream>>>(qw, kw, vw, huw, ff1w, ff2w, wcv);
    bcat_kernel<<<8, 256, 0, stream>>>(qb, kb, vb, qkvb);

    stats_part_kernel<<<dim3(16, 32), 256, 0, stream>>>(x, part1);
    stats_fin_kernel<<<16, 64, 0, stream>>>(part1, mu1, rs1);
    ln_apply_T_kernel<<<dim3(64, 6, 16), 256, 0, stream>>>(x, ln1w, ln1b, mu1, rs1, aT);

    // fused Q|K|V projection: ONE dispatch over N=1920
    gemm_qkv_kernel<<<dim3(32, 15, 16), 256, 0, stream>>>(aT, PX, qwB, qkvb, QT, KT, VT, 384);

    softmax_rows_kernel<<<16384, 256, 0, stream>>>(QT);

    kv_part_kernel<<<dim3(32, 12, 16), 256, 0, stream>>>(KT, VT, KVp, sp);
    kv_fin_kernel<<<dim3(12, 16), 256, 0, stream>>>(KVp, sp, WeffT);

    wtrans_kernel<<<dim3(64, 6, 2), 256, 0, stream>>>(ln2w, ln2b, wT, bT);

    gemm_bt_kernel<<<dim3(3, 6, 16), 256, 0, stream>>>(huwB, 0, WeffT, 294912, nullptr, WcombB, 294912, nullptr, nullptr, 0, 384, 768, 0);

    gemm_bt_kernel<<<dim3(32, 3, 16), 256, 0, stream>>>(QT, PQ, WcombB, 294912, hub, attnT, PX, nullptr, nullptr, 0, 768, 384, 0);

    resid1T_kernel<<<dim3(64, 6, 16), 256, 0, stream>>>(x, attnT, sT, part2);
    stats_fin2_kernel<<<16, 256, 0, stream>>>(part2, mu2, rs2);
    ln2_apply_kernel<<<dim3(768, 16), 256, 0, stream>>>(sT, wT, bT, mu2, rs2, x2T);

    // FFN in 2 chunks of 8 batches (region C free after ln2_apply)
    for (int c = 0; c < 2; ++c) {
        gemm_bt_kernel<<<dim3(32, 12, 8), 256, 0, stream>>>(
            x2T + (long long)c * 8 * PX, PX, ff1wB, 0, ff1b,
            g8, PH, nullptr, nullptr, 0, 384, 1536, 1);
        gemm_bt_kernel<<<dim3(32, 3, 8), 256, 0, stream>>>(
            g8, PH, ff2wB, 0, ff2b,
            nullptr, PX, out + (long long)c * 8 * PX,
            x2T + (long long)c * 8 * PX, PX, 1536, 384, 0);
    }
}

// Round 19
// 735.382 us; speedup vs baseline: 2.0893x; 1.0327x over previous
//
#include <hip/hip_runtime.h>
#include <hip/hip_bf16.h>

using u16 = unsigned short;
typedef __attribute__((ext_vector_type(4))) float f32x4;
typedef __bf16 bf16x8 __attribute__((ext_vector_type(8)));
typedef short s16x4 __attribute__((ext_vector_type(4)));
typedef short s16x8 __attribute__((ext_vector_type(8)));

#define DEVI __device__ __forceinline__

DEVI float b2f(u16 u) {
    union { unsigned i; float f; } x; x.i = ((unsigned)u) << 16; return x.f;
}
DEVI u16 f2b(float f) {
    union { float f; unsigned i; } x; x.f = f;
    unsigned r = (x.i + 0x7fffu + ((x.i >> 16) & 1u)) >> 16;
    return (u16)r;
}

// fast gelu: v * sigmoid(1.5957691 v + 0.0713548 v^3)  (tanh-form, overflow-safe)
DEVI float gelu_fast(float v) {
    float t = v * (1.5957691f + 0.0713548162f * v * v);
    return v / (1.f + __expf(-t));
}

static constexpr long long PX = 1572864LL;  // 384*4096 per batch
static constexpr long long PQ = 3145728LL;  // 768*4096 per batch
static constexpr long long PH = 6291456LL;  // 1536*4096 per batch

DEVI void gl_lds16(const u16* g, u16* l) {
    __builtin_amdgcn_global_load_lds(
        (const __attribute__((address_space(1))) unsigned int*)g,
        (__attribute__((address_space(3))) unsigned int*)l, 16, 0, 0);
}

// ---------------- all weight f32 -> bf16 conversions in ONE launch
__global__ __launch_bounds__(256)
void wconv_kernel(const float* __restrict__ qw, const float* __restrict__ kw,
                  const float* __restrict__ vw, const float* __restrict__ huw,
                  const float* __restrict__ ff1w, const float* __restrict__ ff2w,
                  u16* __restrict__ wcv)
{
    int blk = blockIdx.x;
    const float* src; u16* dst; int lb;
    if      (blk < 288)  { src = qw;   dst = wcv;           lb = blk; }
    else if (blk < 576)  { src = kw;   dst = wcv + 294912;  lb = blk - 288; }
    else if (blk < 720)  { src = vw;   dst = wcv + 589824;  lb = blk - 576; }
    else if (blk < 864)  { src = huw;  dst = wcv + 737280;  lb = blk - 720; }
    else if (blk < 1440) { src = ff1w; dst = wcv + 884736;  lb = blk - 864; }
    else                 { src = ff2w; dst = wcv + 1474560; lb = blk - 1440; }
    int i = (lb * 256 + threadIdx.x) * 4;
    f32x4 v = *(const f32x4*)(src + i);
    s16x4 o;
#pragma unroll
    for (int j = 0; j < 4; ++j) o[j] = (short)f2b(v[j]);
    *(s16x4*)(dst + i) = o;
}

// ---------------- concat q/k/v biases into one 1920-float buffer
__global__ __launch_bounds__(256)
void bcat_kernel(const float* __restrict__ qb, const float* __restrict__ kb,
                 const float* __restrict__ vb, float* __restrict__ o)
{
    int i = blockIdx.x * 256 + threadIdx.x;
    if (i < 768)       o[i] = qb[i];
    else if (i < 1536) o[i] = kb[i - 768];
    else if (i < 1920) o[i] = vb[i - 1536];
}

// ---------------- fused QKV GEMM: one dispatch over N=1920 (=768Q|768K|384V)
__global__ __launch_bounds__(256, 4)
void gemm_qkv_kernel(const u16* __restrict__ A, long long strideA,
                     const u16* __restrict__ Bw,
                     const float* __restrict__ bias,
                     u16* __restrict__ Q, u16* __restrict__ Kd, u16* __restrict__ V,
                     int K)
{
    const int tid = threadIdx.x;
    const int lane = tid & 63;
    const int wv = tid >> 6;
    const int wr = wv >> 1, wc = wv & 1;
    const int l15 = lane & 15, l4 = lane >> 4;
    const int bm = blockIdx.x, bn = blockIdx.y, bz = blockIdx.z;

    A += (long long)bz * strideA;
    u16* dstBase; int Nout; int colBase;
    if (bn < 6)       { dstBase = Q  + (long long)bz * PQ; Nout = 768; colBase = bn * 128; }
    else if (bn < 12) { dstBase = Kd + (long long)bz * PQ; Nout = 768; colBase = (bn - 6) * 128; }
    else              { dstBase = V  + (long long)bz * PX; Nout = 384; colBase = (bn - 12) * 128; }

    __shared__ u16 lds[2][128 * 64];   // 32 KB

    f32x4 acc[4][4] = {};

    auto stage = [&](int kt) {
#pragma unroll
        for (int i = 0; i < 4; ++i) {
            int cid = tid + i * 256;
            int row = cid >> 3, c8 = cid & 7;
            int c8s = c8 ^ (row & 7);
            gl_lds16(A + (long long)(bm * 128 + row) * K + kt + c8s * 8,
                     &lds[0][cid * 8]);
        }
#pragma unroll
        for (int i = 0; i < 4; ++i) {
            int cid = tid + i * 256;
            int row = cid >> 3, c8 = cid & 7;
            int c8s = c8 ^ (row & 7);
            gl_lds16(Bw + (long long)(bn * 128 + row) * K + kt + c8s * 8,
                     &lds[1][cid * 8]);
        }
    };

    auto compute = [&]() {
#pragma unroll
        for (int kk = 0; kk < 2; ++kk) {
            bf16x8 af[4], bfr[4];
#pragma unroll
            for (int mi = 0; mi < 4; ++mi) {
                int row = wr * 64 + mi * 16 + l15;
                int idx8 = (kk * 4 + l4) ^ (row & 7);
                af[mi] = *(const bf16x8*)&lds[0][row * 64 + idx8 * 8];
            }
#pragma unroll
            for (int ni = 0; ni < 4; ++ni) {
                int row = wc * 64 + ni * 16 + l15;
                int idx8 = (kk * 4 + l4) ^ (row & 7);
                bfr[ni] = *(const bf16x8*)&lds[1][row * 64 + idx8 * 8];
            }
#pragma unroll
            for (int mi = 0; mi < 4; ++mi)
#pragma unroll
                for (int ni = 0; ni < 4; ++ni)
                    acc[mi][ni] = __builtin_amdgcn_mfma_f32_16x16x32_bf16(af[mi], bfr[ni], acc[mi][ni], 0, 0, 0);
        }
    };

    stage(0);
    asm volatile("s_waitcnt vmcnt(0)" ::: "memory");
    __syncthreads();
    for (int kt = 64; kt < K; kt += 64) {
        compute();
        __syncthreads();
        stage(kt);
        asm volatile("s_waitcnt vmcnt(0)" ::: "memory");
        __syncthreads();
    }
    compute();

    u16* st = &lds[0][0];            // [64][136]
#pragma unroll
    for (int p = 0; p < 2; ++p) {
        __syncthreads();
        if (wr == p) {
#pragma unroll
            for (int ni = 0; ni < 4; ++ni) {
                int colL = wc * 64 + ni * 16 + l15;
                float bv = bias[bn * 128 + colL];
#pragma unroll
                for (int mi = 0; mi < 4; ++mi) {
#pragma unroll
                    for (int r = 0; r < 4; ++r)
                        st[(mi * 16 + l4 * 4 + r) * 136 + colL] = f2b(acc[mi][ni][r] + bv);
                }
            }
        }
        __syncthreads();
        int lr = tid >> 2, q = tid & 3;
        const u16* src = st + lr * 136 + q * 32;
        u16* dst = dstBase + (long long)(bm * 128 + p * 64 + lr) * Nout + colBase + q * 32;
#pragma unroll
        for (int j = 0; j < 4; ++j)
            *(s16x8*)(dst + j * 8) = *(const s16x8*)(src + j * 8);
    }
}

// ---------------- attn GEMM with FUSED residual-1 + LN2 partial stats:
// sT[token][d] = x[d-major] + (Q @ Wcomb^T + hub); part2[block] = {sum,sumsq}
__global__ __launch_bounds__(256, 4)
void gemm_attn_kernel(const u16* __restrict__ A, long long strideA,
                      const u16* __restrict__ Bw, long long strideB,
                      const float* __restrict__ bias,
                      const float* __restrict__ x,
                      u16* __restrict__ sT,
                      float* __restrict__ part2, int K)
{
    const int tid = threadIdx.x;
    const int lane = tid & 63;
    const int wv = tid >> 6;
    const int wr = wv >> 1, wc = wv & 1;
    const int l15 = lane & 15, l4 = lane >> 4;
    const int bm = blockIdx.x, bn = blockIdx.y, bz = blockIdx.z;

    A  += (long long)bz * strideA;
    Bw += (long long)bz * strideB;
    x  += (long long)bz * PX;
    sT += (long long)bz * PX;

    __shared__ u16 lds[2][128 * 64];   // 32 KB

    f32x4 acc[4][4] = {};

    auto stage = [&](int kt) {
#pragma unroll
        for (int i = 0; i < 4; ++i) {
            int cid = tid + i * 256;
            int row = cid >> 3, c8 = cid & 7;
            int c8s = c8 ^ (row & 7);
            gl_lds16(A + (long long)(bm * 128 + row) * K + kt + c8s * 8,
                     &lds[0][cid * 8]);
        }
#pragma unroll
        for (int i = 0; i < 4; ++i) {
            int cid = tid + i * 256;
            int row = cid >> 3, c8 = cid & 7;
            int c8s = c8 ^ (row & 7);
            gl_lds16(Bw + (long long)(bn * 128 + row) * K + kt + c8s * 8,
                     &lds[1][cid * 8]);
        }
    };

    auto compute = [&]() {
#pragma unroll
        for (int kk = 0; kk < 2; ++kk) {
            bf16x8 af[4], bfr[4];
#pragma unroll
            for (int mi = 0; mi < 4; ++mi) {
                int row = wr * 64 + mi * 16 + l15;
                int idx8 = (kk * 4 + l4) ^ (row & 7);
                af[mi] = *(const bf16x8*)&lds[0][row * 64 + idx8 * 8];
            }
#pragma unroll
            for (int ni = 0; ni < 4; ++ni) {
                int row = wc * 64 + ni * 16 + l15;
                int idx8 = (kk * 4 + l4) ^ (row & 7);
                bfr[ni] = *(const bf16x8*)&lds[1][row * 64 + idx8 * 8];
            }
#pragma unroll
            for (int mi = 0; mi < 4; ++mi)
#pragma unroll
                for (int ni = 0; ni < 4; ++ni)
                    acc[mi][ni] = __builtin_amdgcn_mfma_f32_16x16x32_bf16(af[mi], bfr[ni], acc[mi][ni], 0, 0, 0);
        }
    };

    stage(0);
    asm volatile("s_waitcnt vmcnt(0)" ::: "memory");
    __syncthreads();
    for (int kt = 64; kt < K; kt += 64) {
        compute();
        __syncthreads();
        stage(kt);
        asm volatile("s_waitcnt vmcnt(0)" ::: "memory");
        __syncthreads();
    }
    compute();

    // fused epilogue: add hub + x (d-major), stage, coalesced sT store, stats
    u16* st = &lds[0][0];            // [64][136]
    float ps = 0.f, pq = 0.f;
#pragma unroll
    for (int p = 0; p < 2; ++p) {
        __syncthreads();
        if (wr == p) {
#pragma unroll
            for (int ni = 0; ni < 4; ++ni) {
                int colL = wc * 64 + ni * 16 + l15;
                int colG = bn * 128 + colL;
                float bv = bias[colG];
#pragma unroll
                for (int mi = 0; mi < 4; ++mi) {
                    const float* xp = x + (long long)colG * 4096 + bm * 128 + p * 64 + mi * 16 + l4 * 4;
                    f32x4 xv = *(const f32x4*)xp;
#pragma unroll
                    for (int r = 0; r < 4; ++r)
                        st[(mi * 16 + l4 * 4 + r) * 136 + colL] = f2b(acc[mi][ni][r] + bv + xv[r]);
                }
            }
        }
        __syncthreads();
        int lr = tid >> 2, q = tid & 3;
        const u16* src = st + lr * 136 + q * 32;
        u16* dst = sT + (long long)(bm * 128 + p * 64 + lr) * 384 + bn * 128 + q * 32;
#pragma unroll
        for (int j = 0; j < 4; ++j) {
            s16x8 v = *(const s16x8*)(src + j * 8);
            *(s16x8*)(dst + j * 8) = v;
#pragma unroll
            for (int e = 0; e < 8; ++e) { float f = b2f((u16)v[e]); ps += f; pq += f * f; }
        }
    }

    for (int off = 32; off; off >>= 1) { ps += __shfl_down(ps, off); pq += __shfl_down(pq, off); }
    __shared__ float rs[4], rq[4];
    if (lane == 0) { rs[wv] = ps; rq[wv] = pq; }
    __syncthreads();
    if (tid == 0) {
        int bid = bz * 96 + bm * 3 + bn;
        part2[bid * 2 + 0] = rs[0] + rs[1] + rs[2] + rs[3];
        part2[bid * 2 + 1] = rq[0] + rq[1] + rq[2] + rq[3];
    }
}

// ---------------- GEMM 128x128 (R10 structure), bf16 or f32-dmajor epilogue
__global__ __launch_bounds__(256, 4)
void gemm_bt_kernel(const u16* __restrict__ A, long long strideA,
                    const u16* __restrict__ Bw, long long strideB,
                    const float* __restrict__ bias,
                    u16* __restrict__ C, long long strideC,
                    float* __restrict__ Cf,
                    const u16* __restrict__ addT, long long strideAdd,
                    int K, int N, int doGelu)
{
    const int tid = threadIdx.x;
    const int lane = tid & 63;
    const int wv = tid >> 6;
    const int wr = wv >> 1, wc = wv & 1;
    const int l15 = lane & 15, l4 = lane >> 4;
    const int bm = blockIdx.x, bn = blockIdx.y, bz = blockIdx.z;

    A  += (long long)bz * strideA;
    Bw += (long long)bz * strideB;
    if (C)    C    += (long long)bz * strideC;
    if (Cf)   Cf   += (long long)bz * strideC;
    if (addT) addT += (long long)bz * strideAdd;

    __shared__ u16 lds[2][128 * 64];   // 32 KB

    f32x4 acc[4][4] = {};

    auto stage = [&](int kt) {
#pragma unroll
        for (int i = 0; i < 4; ++i) {
            int cid = tid + i * 256;
            int row = cid >> 3, c8 = cid & 7;
            int c8s = c8 ^ (row & 7);
            gl_lds16(A + (long long)(bm * 128 + row) * K + kt + c8s * 8,
                     &lds[0][cid * 8]);
        }
#pragma unroll
        for (int i = 0; i < 4; ++i) {
            int cid = tid + i * 256;
            int row = cid >> 3, c8 = cid & 7;
            int c8s = c8 ^ (row & 7);
            gl_lds16(Bw + (long long)(bn * 128 + row) * K + kt + c8s * 8,
                     &lds[1][cid * 8]);
        }
    };

    auto compute = [&]() {
#pragma unroll
        for (int kk = 0; kk < 2; ++kk) {
            bf16x8 af[4], bfr[4];
#pragma unroll
            for (int mi = 0; mi < 4; ++mi) {
                int row = wr * 64 + mi * 16 + l15;
                int idx8 = (kk * 4 + l4) ^ (row & 7);
                af[mi] = *(const bf16x8*)&lds[0][row * 64 + idx8 * 8];
            }
#pragma unroll
            for (int ni = 0; ni < 4; ++ni) {
                int row = wc * 64 + ni * 16 + l15;
                int idx8 = (kk * 4 + l4) ^ (row & 7);
                bfr[ni] = *(const bf16x8*)&lds[1][row * 64 + idx8 * 8];
            }
#pragma unroll
            for (int mi = 0; mi < 4; ++mi)
#pragma unroll
                for (int ni = 0; ni < 4; ++ni)
                    acc[mi][ni] = __builtin_amdgcn_mfma_f32_16x16x32_bf16(af[mi], bfr[ni], acc[mi][ni], 0, 0, 0);
        }
    };

    stage(0);
    asm volatile("s_waitcnt vmcnt(0)" ::: "memory");
    __syncthreads();
    for (int kt = 64; kt < K; kt += 64) {
        compute();
        __syncthreads();
        stage(kt);
        asm volatile("s_waitcnt vmcnt(0)" ::: "memory");
        __syncthreads();
    }
    compute();

    if (!Cf) {
        u16* st = &lds[0][0];            // [64][136]
#pragma unroll
        for (int p = 0; p < 2; ++p) {
            __syncthreads();
            if (wr == p) {
#pragma unroll
                for (int ni = 0; ni < 4; ++ni) {
                    int colL = wc * 64 + ni * 16 + l15;
                    float bv = bias ? bias[bn * 128 + colL] : 0.f;
#pragma unroll
                    for (int mi = 0; mi < 4; ++mi) {
#pragma unroll
                        for (int r = 0; r < 4; ++r) {
                            float v = acc[mi][ni][r] + bv;
                            if (doGelu) v = gelu_fast(v);
                            st[(mi * 16 + l4 * 4 + r) * 136 + colL] = f2b(v);
                        }
                    }
                }
            }
            __syncthreads();
            int lr = tid >> 2, q = tid & 3;
            const u16* src = st + lr * 136 + q * 32;
            u16* dst = C + (long long)(bm * 128 + p * 64 + lr) * N + bn * 128 + q * 32;
#pragma unroll
            for (int j = 0; j < 4; ++j)
                *(s16x8*)(dst + j * 8) = *(const s16x8*)(src + j * 8);
        }
    } else {
        float* stf = (float*)&lds[0][0];   // [32][132]
#pragma unroll
        for (int p = 0; p < 4; ++p) {
            __syncthreads();
            if (wc == (p >> 1)) {
#pragma unroll
                for (int nj = 0; nj < 2; ++nj) {
                    int ni = (p & 1) * 2 + nj;
                    int colL = wc * 64 + ni * 16 + l15;
                    int lc = nj * 16 + l15;
                    float bv = bias ? bias[bn * 128 + colL] : 0.f;
#pragma unroll
                    for (int mi = 0; mi < 4; ++mi) {
                        int row0 = wr * 64 + mi * 16 + l4 * 4;
#pragma unroll
                        for (int r = 0; r < 4; ++r) {
                            float v = acc[mi][ni][r] + bv
                                    + b2f(addT[(long long)(bm * 128 + row0 + r) * N + bn * 128 + colL]);
                            stf[lc * 132 + row0 + r] = v;
                        }
                    }
                }
            }
            __syncthreads();
            int lc = tid >> 3, q = tid & 7;
            float* dst = Cf + (long long)(bn * 128 + p * 32 + lc) * 4096 + bm * 128 + q * 16;
            const float* src = stf + lc * 132 + q * 16;
#pragma unroll
            for (int j = 0; j < 4; ++j)
                *(f32x4*)(dst + j * 4) = *(const f32x4*)(src + j * 4);
        }
    }
}

// ---------------- per-batch sum / sumsq partials over 1572864 f32 elems
__global__ __launch_bounds__(256)
void stats_part_kernel(const float* __restrict__ x, float* __restrict__ part)
{
    int b = blockIdx.x, cb = blockIdx.y, t = threadIdx.x;
    const float* p = x + (long long)b * PX + (long long)cb * 49152;
    float s = 0.f, q = 0.f;
    for (int i = 0; i < 48; ++i) {
        f32x4 v = *(const f32x4*)(p + (i * 256 + t) * 4);
#pragma unroll
        for (int j = 0; j < 4; ++j) { s += v[j]; q += v[j] * v[j]; }
    }
    for (int off = 32; off; off >>= 1) { s += __shfl_down(s, off); q += __shfl_down(q, off); }
    __shared__ float rs[4], rq[4];
    if ((t & 63) == 0) { rs[t >> 6] = s; rq[t >> 6] = q; }
    __syncthreads();
    if (t == 0) {
        part[(b * 32 + cb) * 2 + 0] = rs[0] + rs[1] + rs[2] + rs[3];
        part[(b * 32 + cb) * 2 + 1] = rq[0] + rq[1] + rq[2] + rq[3];
    }
}

__global__ void stats_fin_kernel(const float* __restrict__ part, float* __restrict__ mu, float* __restrict__ rsg)
{
    int b = blockIdx.x, l = threadIdx.x;
    float s = l < 32 ? part[(b * 32 + l) * 2 + 0] : 0.f;
    float q = l < 32 ? part[(b * 32 + l) * 2 + 1] : 0.f;
    for (int off = 32; off; off >>= 1) { s += __shfl_down(s, off); q += __shfl_down(q, off); }
    if (l == 0) {
        float m = s / 1572864.f;
        float v = q / 1572864.f - m * m; v = fmaxf(v, 0.f);
        mu[b] = m; rsg[b] = rsqrtf(v + 1e-5f);
    }
}

// ---------------- LN1 apply (f32 src, d-major) -> T-layout bf16
__global__ __launch_bounds__(256)
void ln_apply_T_kernel(const float* __restrict__ src, const float* __restrict__ w, const float* __restrict__ bb,
                       const float* __restrict__ mu, const float* __restrict__ rsg, u16* __restrict__ dstT)
{
    int nt = blockIdx.x, dt = blockIdx.y, b = blockIdx.z;
    int t = threadIdx.x, tx = t & 63, ty = t >> 6;
    __shared__ float tile[64][65];
    float m = mu[b], r = rsg[b];
    const long long base = (long long)b * PX;
#pragma unroll 4
    for (int i = 0; i < 16; ++i) {
        int dy = ty + i * 4;
        int d = dt * 64 + dy, n = nt * 64 + tx;
        long long widx = (long long)d * 4096 + n;
        tile[dy][tx] = (src[base + widx] - m) * r * w[widx] + bb[widx];
    }
    __syncthreads();
#pragma unroll 4
    for (int i = 0; i < 16; ++i) {
        int ny = ty + i * 4;
        int n = nt * 64 + ny, d = dt * 64 + tx;
        dstT[base + (long long)n * 384 + d] = f2b(tile[tx][ny]);
    }
}

// ---------------- row softmax over 768 contiguous channels (Q), in place
__global__ __launch_bounds__(256)
void softmax_rows_kernel(u16* __restrict__ QT)
{
    long long row = (long long)blockIdx.x * 4 + (threadIdx.x >> 6);
    int lane = threadIdx.x & 63;
    u16* p = QT + row * 768;
    float v[12];
#pragma unroll
    for (int g = 0; g < 3; ++g) {
        s16x4 a = *(const s16x4*)(p + g * 256 + lane * 4);
#pragma unroll
        for (int j = 0; j < 4; ++j) v[g * 4 + j] = b2f((u16)a[j]);
    }
    float m = -1e30f;
#pragma unroll
    for (int j = 0; j < 12; ++j) m = fmaxf(m, v[j]);
    for (int off = 32; off; off >>= 1) m = fmaxf(m, __shfl_xor(m, off));
    float s = 0.f;
#pragma unroll
    for (int j = 0; j < 12; ++j) { v[j] = __expf(v[j] - m); s += v[j]; }
    for (int off = 32; off; off >>= 1) s += __shfl_xor(s, off);
    float inv = 1.f / s;
#pragma unroll
    for (int g = 0; g < 3; ++g) {
        s16x4 o;
#pragma unroll
        for (int j = 0; j < 4; ++j) o[j] = (short)f2b(v[g * 4 + j] * inv);
        *(s16x4*)(p + g * 256 + lane * 4) = o;
    }
}

// ---------------- KV partials via MFMA, no-max exp (inputs bounded), CHUNK=128
__global__ __launch_bounds__(256)
void kv_part_kernel(const u16* __restrict__ KT, const u16* __restrict__ VT,
                    u16* __restrict__ KVp, float* __restrict__ sp)
{
    const int ch = blockIdx.x, h = blockIdx.y, b = blockIdx.z;
    const int t = threadIdx.x;
    const int lane = t & 63, w = t >> 6;

    __shared__ u16 kraw[128 * 64];
    __shared__ u16 eKT[64 * 128];
    __shared__ u16 Vt[32 * 128];
    __shared__ float reds[4][64];

    const u16* Kp = KT + (long long)b * PQ + (long long)(ch * 128) * 768 + h * 64;
    const u16* Vp = VT + (long long)b * PX + (long long)(ch * 128) * 384 + h * 32;

#pragma unroll
    for (int pass = 0; pass < 4; ++pass) {
        int cid = t + pass * 256;
        int row = cid >> 3, c8 = cid & 7;
        gl_lds16(Kp + (long long)row * 768 + c8 * 8, kraw + cid * 8);
    }

    {
        int v0 = (t & 7) * 4;
#pragma unroll
        for (int pass = 0; pass < 4; ++pass) {
            int n = (t >> 3) + pass * 32;
            s16x4 v4 = *(const s16x4*)(Vp + (long long)n * 384 + v0);
#pragma unroll
            for (int j = 0; j < 4; ++j) {
                int row = v0 + j;
                Vt[row * 128 + (n ^ ((row & 7) << 3))] = (u16)v4[j];
            }
        }
    }

    asm volatile("s_waitcnt vmcnt(0)" ::: "memory");
    __syncthreads();

    const int c = lane;
    {
        float s = 0.f;
        const int swz = (c & 7) << 3;
#pragma unroll
        for (int r8 = 0; r8 < 4; ++r8) {
            int rbase = w * 32 + r8 * 8;
            s16x8 buf;
#pragma unroll
            for (int j = 0; j < 8; ++j) {
                float e = __expf(b2f(kraw[(rbase + j) * 64 + c]));
                s += e;
                buf[j] = (short)f2b(e);
            }
            *(s16x8*)&eKT[c * 128 + (rbase ^ swz)] = buf;
        }
        reds[w][c] = s;
    }
    __syncthreads();

    if (t < 64)
        sp[((long long)(b * 12 + h) * 32 + ch) * 64 + t] =
            reds[0][t] + reds[1][t] + reds[2][t] + reds[3][t];

    const int l15 = lane & 15, l4 = lane >> 4;
    const int qrow = w * 16 + l15;
    const int sa = (qrow & 7) << 3;
    const int v0row = l15, v1row = 16 + l15;
    const int s0 = (v0row & 7) << 3, s1 = (v1row & 7) << 3;
    f32x4 acc0 = {}, acc1 = {};
#pragma unroll
    for (int ns = 0; ns < 4; ++ns) {
        int na = ns * 32 + l4 * 8;
        bf16x8 a  = *(const bf16x8*)&eKT[qrow * 128 + (na ^ sa)];
        bf16x8 b0 = *(const bf16x8*)&Vt[v0row * 128 + (na ^ s0)];
        bf16x8 b1 = *(const bf16x8*)&Vt[v1row * 128 + (na ^ s1)];
        acc0 = __builtin_amdgcn_mfma_f32_16x16x32_bf16(a, b0, acc0, 0, 0, 0);
        acc1 = __builtin_amdgcn_mfma_f32_16x16x32_bf16(a, b1, acc1, 0, 0, 0);
    }
    u16* Kb = KVp + ((long long)(b * 12 + h) * 32 + ch) * 2048;
#pragma unroll
    for (int r = 0; r < 4; ++r) {
        int q = w * 16 + l4 * 4 + r;
        Kb[q * 32 + l15]      = f2b(acc0[r]);
        Kb[q * 32 + 16 + l15] = f2b(acc1[r]);
    }
}

// ---------------- merge 32 KV partials -> WeffT (768 x 384 per batch)
__global__ __launch_bounds__(256)
void kv_fin_kernel(const u16* __restrict__ KVp, const float* __restrict__ sp,
                   u16* __restrict__ WeffT)
{
    const int h = blockIdx.x, b = blockIdx.y;
    const int t = threadIdx.x;
    __shared__ float fac[64];
    __shared__ float kvt[32][64];

    const long long pb = (long long)(b * 12 + h) * 32;
    if (t < 64) {
        float s = 0.f;
#pragma unroll
        for (int ch = 0; ch < 32; ++ch) s += sp[(pb + ch) * 64 + t];
        fac[t] = 1.f / (s * 4096.f);
    }
    __syncthreads();

    const int v0 = (t & 3) * 8, q = t >> 2;
    float acc[8] = {};
#pragma unroll
    for (int ch = 0; ch < 32; ++ch) {
        s16x8 kv8 = *(const s16x8*)&KVp[(pb + ch) * 2048 + q * 32 + v0];
#pragma unroll
        for (int j = 0; j < 8; ++j) acc[j] += b2f((u16)kv8[j]);
    }
    float fq = fac[q];
#pragma unroll
    for (int j = 0; j < 8; ++j) kvt[v0 + j][q] = acc[j] * fq;
    __syncthreads();

    u16* Wb = WeffT + (long long)b * 294912;
    for (int i = t; i < 64 * 384; i += 256) {
        int qq = i / 384, cc = i % 384;
        int cv = cc - h * 32;
        float val = (cv >= 0 && cv < 32) ? kvt[cv][qq] : 0.f;
        Wb[(long long)(h * 64 + qq) * 384 + cc] = f2b(val);
    }
}

// ---------------- transpose LN2 weight/bias (f32 d-major) -> bf16 T-layout
__global__ __launch_bounds__(256)
void wtrans_kernel(const float* __restrict__ w, const float* __restrict__ bb,
                   u16* __restrict__ wT, u16* __restrict__ bT)
{
    int nt = blockIdx.x, dt = blockIdx.y;
    const float* src = blockIdx.z ? bb : w;
    u16* dst = blockIdx.z ? bT : wT;
    int t = threadIdx.x, tx = t & 63, ty = t >> 6;
    __shared__ float tile[64][65];
#pragma unroll 4
    for (int i = 0; i < 16; ++i) {
        int dy = ty + i * 4;
        tile[dy][tx] = src[(long long)(dt * 64 + dy) * 4096 + nt * 64 + tx];
    }
    __syncthreads();
#pragma unroll 4
    for (int i = 0; i < 16; ++i) {
        int ny = ty + i * 4;
        dst[(long long)(nt * 64 + ny) * 384 + dt * 64 + tx] = f2b(tile[tx][ny]);
    }
}

// ---------------- LN2 stats finalize from 96 partials/batch
__global__ __launch_bounds__(256)
void stats_fin2_kernel(const float* __restrict__ part2, float* __restrict__ mu, float* __restrict__ rsg)
{
    int b = blockIdx.x, t = threadIdx.x;
    float s = 0.f, q = 0.f;
    if (t < 96) { s = part2[(b * 96 + t) * 2]; q = part2[(b * 96 + t) * 2 + 1]; }
    for (int off = 32; off; off >>= 1) { s += __shfl_down(s, off); q += __shfl_down(q, off); }
    __shared__ float rs[4], rq[4];
    if ((t & 63) == 0) { rs[t >> 6] = s; rq[t >> 6] = q; }
    __syncthreads();
    if (t == 0) {
        float S = rs[0] + rs[1] + rs[2] + rs[3], Q = rq[0] + rq[1] + rq[2] + rq[3];
        float m = S / 1572864.f;
        float v = Q / 1572864.f - m * m; v = fmaxf(v, 0.f);
        mu[b] = m; rsg[b] = rsqrtf(v + 1e-5f);
    }
}

// ---------------- LN2 apply: elementwise T-layout, all bf16
__global__ __launch_bounds__(256)
void ln2_apply_kernel(const u16* __restrict__ sT, const u16* __restrict__ wT, const u16* __restrict__ bT,
                      const float* __restrict__ mu, const float* __restrict__ rsg, u16* __restrict__ x2T)
{
    int blk = blockIdx.x, b = blockIdx.y, t = threadIdx.x;
    float m = mu[b], r = rsg[b];
    long long wi = (long long)blk * 2048 + t * 8;
    long long gi = (long long)b * PX + wi;
    s16x8 sv = *(const s16x8*)(sT + gi);
    s16x8 wv = *(const s16x8*)(wT + wi);
    s16x8 bv = *(const s16x8*)(bT + wi);
    s16x8 o;
#pragma unroll
    for (int j = 0; j < 8; ++j)
        o[j] = (short)f2b((b2f((u16)sv[j]) - m) * r * b2f((u16)wv[j]) + b2f((u16)bv[j]));
    *(s16x8*)(x2T + gi) = o;
}

extern "C" void kernel_launch(void* const* d_in, const int* in_sizes, int n_in,
                              void* d_out, int out_size, void* d_ws, size_t ws_size,
                              hipStream_t stream)
{
    const float* x    = (const float*)d_in[0];
    const float* ln1w = (const float*)d_in[1];
    const float* ln1b = (const float*)d_in[2];
    const float* qw   = (const float*)d_in[3];
    const float* qb   = (const float*)d_in[4];
    const float* kw   = (const float*)d_in[5];
    const float* kb   = (const float*)d_in[6];
    const float* vw   = (const float*)d_in[7];
    const float* vb   = (const float*)d_in[8];
    const float* huw  = (const float*)d_in[9];
    const float* hub  = (const float*)d_in[10];
    const float* ln2w = (const float*)d_in[11];
    const float* ln2b = (const float*)d_in[12];
    const float* ff1w = (const float*)d_in[13];
    const float* ff1b = (const float*)d_in[14];
    const float* ff2w = (const float*)d_in[15];
    const float* ff2b = (const float*)d_in[16];
    float* out = (float*)d_out;

    char* ws = (char*)d_ws;
    u16*   aT    = (u16*)(ws + 0);                 //  50.3 MB region A
    u16*   QT    = (u16*)(ws + 50331648LL);        // 100.7 MB region B
    u16*   KT    = (u16*)(ws + 150994944LL);       // 100.7 MB region C
    u16*   VT    = (u16*)(ws + 251658240LL);       //  50.3 MB region D
    u16*   WeffT = (u16*)(ws + 301989888LL);       //   9.4 MB region E
    u16*   wcv   = (u16*)(ws + 311427072LL);       //   4.1 MB
    float* fbuf  = (float*)(ws + 315555840LL);     //  ~64 KB

    // region A overlays (aT dead after QKV GEMM):
    u16*   KVp    = (u16*)(ws + 0);                // 25,165,824 B
    float* sp     = (float*)(ws + 25165824LL);     //  1,572,864 B
    u16*   WcombB = (u16*)(ws + 27525120LL);       //  9,437,184 B

    // region C overlays (KT dead after kv_part):
    u16* sT = KT;                                       // 50.3 MB
    u16* wT = (u16*)(ws + 150994944LL + 50331648LL);    //  3.1 MB
    u16* bT = (u16*)(ws + 150994944LL + 53477376LL);    //  3.1 MB
    u16* g8 = KT;                                       // 100.66 MB (after ln2_apply)

    u16* x2T = QT;

    u16* qwB   = wcv;        // rows 0..1919 of the fused qkv weight
    u16* ff1wB = wcv + 884736;
    u16* ff2wB = wcv + 1474560;
    u16* huwB  = wcv + 737280;

    float* part1 = fbuf;               // 1024
    float* mu1   = fbuf + 1024;        // 16
    float* rs1   = fbuf + 1040;        // 16
    float* part2 = fbuf + 1056;        // 3072 (96*16*2)
    float* mu2   = part2 + 3072;       // 16
    float* rs2   = mu2 + 16;           // 16
    float* qkvb  = rs2 + 16;           // 1920

    wconv_kernel<<<2016, 256, 0, stream>>>(qw, kw, vw, huw, ff1w, ff2w, wcv);
    bcat_kernel<<<8, 256, 0, stream>>>(qb, kb, vb, qkvb);

    stats_part_kernel<<<dim3(16, 32), 256, 0, stream>>>(x, part1);
    stats_fin_kernel<<<16, 64, 0, stream>>>(part1, mu1, rs1);
    ln_apply_T_kernel<<<dim3(64, 6, 16), 256, 0, stream>>>(x, ln1w, ln1b, mu1, rs1, aT);

    // fused Q|K|V projection: ONE dispatch over N=1920
    gemm_qkv_kernel<<<dim3(32, 15, 16), 256, 0, stream>>>(aT, PX, qwB, qkvb, QT, KT, VT, 384);

    softmax_rows_kernel<<<16384, 256, 0, stream>>>(QT);

    kv_part_kernel<<<dim3(32, 12, 16), 256, 0, stream>>>(KT, VT, KVp, sp);
    kv_fin_kernel<<<dim3(12, 16), 256, 0, stream>>>(KVp, sp, WeffT);

    wtrans_kernel<<<dim3(64, 6, 2), 256, 0, stream>>>(ln2w, ln2b, wT, bT);

    // Wcomb = huw @ Weff (per batch)
    gemm_bt_kernel<<<dim3(3, 6, 16), 256, 0, stream>>>(huwB, 0, WeffT, 294912, nullptr, WcombB, 294912, nullptr, nullptr, 0, 384, 768, 0);

    // attn GEMM with FUSED residual-1 + LN2 partials -> sT + part2
    gemm_attn_kernel<<<dim3(32, 3, 16), 256, 0, stream>>>(QT, PQ, WcombB, 294912, hub, x, sT, part2, 768);

    stats_fin2_kernel<<<16, 256, 0, stream>>>(part2, mu2, rs2);
    ln2_apply_kernel<<<dim3(768, 16), 256, 0, stream>>>(sT, wT, bT, mu2, rs2, x2T);

    // FFN in 2 chunks of 8 batches (region C free after ln2_apply)
    for (int c = 0; c < 2; ++c) {
        gemm_bt_kernel<<<dim3(32, 12, 8), 256, 0, stream>>>(
            x2T + (long long)c * 8 * PX, PX, ff1wB, 0, ff1b,
            g8, PH, nullptr, nullptr, 0, 384, 1536, 1);
        gemm_bt_kernel<<<dim3(32, 3, 8), 256, 0, stream>>>(
            g8, PH, ff2wB, 0, ff2b,
            nullptr, PX, out + (long long)c * 8 * PX,
            x2T + (long long)c * 8 * PX, PX, 1536, 384, 0);
    }
}

// Round 20
// 693.515 us; speedup vs baseline: 2.2154x; 1.0604x over previous
//
#include <hip/hip_runtime.h>
#include <hip/hip_bf16.h>

using u16 = unsigned short;
typedef __attribute__((ext_vector_type(4))) float f32x4;
typedef __bf16 bf16x8 __attribute__((ext_vector_type(8)));
typedef short s16x4 __attribute__((ext_vector_type(4)));
typedef short s16x8 __attribute__((ext_vector_type(8)));

#define DEVI __device__ __forceinline__

DEVI float b2f(u16 u) {
    union { unsigned i; float f; } x; x.i = ((unsigned)u) << 16; return x.f;
}
DEVI u16 f2b(float f) {
    union { float f; unsigned i; } x; x.f = f;
    unsigned r = (x.i + 0x7fffu + ((x.i >> 16) & 1u)) >> 16;
    return (u16)r;
}

// fast gelu: v * sigmoid(1.5957691 v + 0.0713548 v^3)  (tanh-form, overflow-safe)
DEVI float gelu_fast(float v) {
    float t = v * (1.5957691f + 0.0713548162f * v * v);
    return v / (1.f + __expf(-t));
}

static constexpr long long PX = 1572864LL;  // 384*4096 per batch
static constexpr long long PQ = 3145728LL;  // 768*4096 per batch
static constexpr long long PH = 6291456LL;  // 1536*4096 per batch

DEVI void gl_lds16(const u16* g, u16* l) {
    __builtin_amdgcn_global_load_lds(
        (const __attribute__((address_space(1))) unsigned int*)g,
        (__attribute__((address_space(3))) unsigned int*)l, 16, 0, 0);
}

// ---------------- all weight f32 -> bf16 conversions in ONE launch
__global__ __launch_bounds__(256)
void wconv_kernel(const float* __restrict__ qw, const float* __restrict__ kw,
                  const float* __restrict__ vw, const float* __restrict__ huw,
                  const float* __restrict__ ff1w, const float* __restrict__ ff2w,
                  u16* __restrict__ wcv)
{
    int blk = blockIdx.x;
    const float* src; u16* dst; int lb;
    if      (blk < 288)  { src = qw;   dst = wcv;           lb = blk; }
    else if (blk < 576)  { src = kw;   dst = wcv + 294912;  lb = blk - 288; }
    else if (blk < 720)  { src = vw;   dst = wcv + 589824;  lb = blk - 576; }
    else if (blk < 864)  { src = huw;  dst = wcv + 737280;  lb = blk - 720; }
    else if (blk < 1440) { src = ff1w; dst = wcv + 884736;  lb = blk - 864; }
    else                 { src = ff2w; dst = wcv + 1474560; lb = blk - 1440; }
    int i = (lb * 256 + threadIdx.x) * 4;
    f32x4 v = *(const f32x4*)(src + i);
    s16x4 o;
#pragma unroll
    for (int j = 0; j < 4; ++j) o[j] = (short)f2b(v[j]);
    *(s16x4*)(dst + i) = o;
}

// ---------------- concat q/k/v biases into one 1920-float buffer
__global__ __launch_bounds__(256)
void bcat_kernel(const float* __restrict__ qb, const float* __restrict__ kb,
                 const float* __restrict__ vb, float* __restrict__ o)
{
    int i = blockIdx.x * 256 + threadIdx.x;
    if (i < 768)       o[i] = qb[i];
    else if (i < 1536) o[i] = kb[i - 768];
    else if (i < 1920) o[i] = vb[i - 1536];
}

// ---------------- fused QKV GEMM over N=1920 (=768Q|768K|384V).
// Q tiles (bn<6): writes exp(Q) (no-max softmax numerator; inputs bounded)
// and per-block softmax row-sum partials rsump[(bz*6+bn)*4096 + row].
__global__ __launch_bounds__(256, 4)
void gemm_qkv_kernel(const u16* __restrict__ A, long long strideA,
                     const u16* __restrict__ Bw,
                     const float* __restrict__ bias,
                     u16* __restrict__ Q, u16* __restrict__ Kd, u16* __restrict__ V,
                     float* __restrict__ rsump, int K)
{
    const int tid = threadIdx.x;
    const int lane = tid & 63;
    const int wv = tid >> 6;
    const int wr = wv >> 1, wc = wv & 1;
    const int l15 = lane & 15, l4 = lane >> 4;
    const int bm = blockIdx.x, bn = blockIdx.y, bz = blockIdx.z;

    A += (long long)bz * strideA;
    u16* dstBase; int Nout; int colBase;
    if (bn < 6)       { dstBase = Q  + (long long)bz * PQ; Nout = 768; colBase = bn * 128; }
    else if (bn < 12) { dstBase = Kd + (long long)bz * PQ; Nout = 768; colBase = (bn - 6) * 128; }
    else              { dstBase = V  + (long long)bz * PX; Nout = 384; colBase = (bn - 12) * 128; }
    const bool isQ = (bn < 6);

    __shared__ u16 lds[2][128 * 64];   // 32 KB

    f32x4 acc[4][4] = {};

    auto stage = [&](int kt) {
#pragma unroll
        for (int i = 0; i < 4; ++i) {
            int cid = tid + i * 256;
            int row = cid >> 3, c8 = cid & 7;
            int c8s = c8 ^ (row & 7);
            gl_lds16(A + (long long)(bm * 128 + row) * K + kt + c8s * 8,
                     &lds[0][cid * 8]);
        }
#pragma unroll
        for (int i = 0; i < 4; ++i) {
            int cid = tid + i * 256;
            int row = cid >> 3, c8 = cid & 7;
            int c8s = c8 ^ (row & 7);
            gl_lds16(Bw + (long long)(bn * 128 + row) * K + kt + c8s * 8,
                     &lds[1][cid * 8]);
        }
    };

    auto compute = [&]() {
#pragma unroll
        for (int kk = 0; kk < 2; ++kk) {
            bf16x8 af[4], bfr[4];
#pragma unroll
            for (int mi = 0; mi < 4; ++mi) {
                int row = wr * 64 + mi * 16 + l15;
                int idx8 = (kk * 4 + l4) ^ (row & 7);
                af[mi] = *(const bf16x8*)&lds[0][row * 64 + idx8 * 8];
            }
#pragma unroll
            for (int ni = 0; ni < 4; ++ni) {
                int row = wc * 64 + ni * 16 + l15;
                int idx8 = (kk * 4 + l4) ^ (row & 7);
                bfr[ni] = *(const bf16x8*)&lds[1][row * 64 + idx8 * 8];
            }
#pragma unroll
            for (int mi = 0; mi < 4; ++mi)
#pragma unroll
                for (int ni = 0; ni < 4; ++ni)
                    acc[mi][ni] = __builtin_amdgcn_mfma_f32_16x16x32_bf16(af[mi], bfr[ni], acc[mi][ni], 0, 0, 0);
        }
    };

    stage(0);
    asm volatile("s_waitcnt vmcnt(0)" ::: "memory");
    __syncthreads();
    for (int kt = 64; kt < K; kt += 64) {
        compute();
        __syncthreads();
        stage(kt);
        asm volatile("s_waitcnt vmcnt(0)" ::: "memory");
        __syncthreads();
    }
    compute();

    u16* st = &lds[0][0];            // [64][136]
#pragma unroll
    for (int p = 0; p < 2; ++p) {
        __syncthreads();
        if (wr == p) {
#pragma unroll
            for (int ni = 0; ni < 4; ++ni) {
                int colL = wc * 64 + ni * 16 + l15;
                float bv = bias[bn * 128 + colL];
#pragma unroll
                for (int mi = 0; mi < 4; ++mi) {
#pragma unroll
                    for (int r = 0; r < 4; ++r) {
                        float v = acc[mi][ni][r] + bv;
                        if (isQ) v = __expf(v);
                        st[(mi * 16 + l4 * 4 + r) * 136 + colL] = f2b(v);
                    }
                }
            }
        }
        __syncthreads();
        int lr = tid >> 2, q = tid & 3;
        const u16* src = st + lr * 136 + q * 32;
        u16* dst = dstBase + (long long)(bm * 128 + p * 64 + lr) * Nout + colBase + q * 32;
        float s = 0.f;
#pragma unroll
        for (int j = 0; j < 4; ++j) {
            s16x8 v8 = *(const s16x8*)(src + j * 8);
            *(s16x8*)(dst + j * 8) = v8;
            if (isQ) {
#pragma unroll
                for (int e = 0; e < 8; ++e) s += b2f((u16)v8[e]);
            }
        }
        if (isQ) {
            s += __shfl_xor(s, 1);
            s += __shfl_xor(s, 2);
            if (q == 0)
                rsump[((long long)(bz * 6 + bn)) * 4096 + bm * 128 + p * 64 + lr] = s;
        }
    }
}

// ---------------- attn GEMM: acc*rowscale + hub + x  -> sT, + LN2 partials
__global__ __launch_bounds__(256, 4)
void gemm_attn_kernel(const u16* __restrict__ A, long long strideA,
                      const u16* __restrict__ Bw, long long strideB,
                      const float* __restrict__ bias,
                      const float* __restrict__ x,
                      const float* __restrict__ rsump,
                      u16* __restrict__ sT,
                      float* __restrict__ part2, int K)
{
    const int tid = threadIdx.x;
    const int lane = tid & 63;
    const int wv = tid >> 6;
    const int wr = wv >> 1, wc = wv & 1;
    const int l15 = lane & 15, l4 = lane >> 4;
    const int bm = blockIdx.x, bn = blockIdx.y, bz = blockIdx.z;

    A  += (long long)bz * strideA;
    Bw += (long long)bz * strideB;
    x  += (long long)bz * PX;
    sT += (long long)bz * PX;

    __shared__ u16 lds[2][128 * 64];   // 32 KB
    __shared__ float sscale[128];

    // per-row softmax scale = 1 / sum of the 6 column-block partials
    if (tid < 128) {
        float s = 0.f;
#pragma unroll
        for (int j = 0; j < 6; ++j)
            s += rsump[((long long)(bz * 6 + j)) * 4096 + bm * 128 + tid];
        sscale[tid] = 1.f / s;
    }

    f32x4 acc[4][4] = {};

    auto stage = [&](int kt) {
#pragma unroll
        for (int i = 0; i < 4; ++i) {
            int cid = tid + i * 256;
            int row = cid >> 3, c8 = cid & 7;
            int c8s = c8 ^ (row & 7);
            gl_lds16(A + (long long)(bm * 128 + row) * K + kt + c8s * 8,
                     &lds[0][cid * 8]);
        }
#pragma unroll
        for (int i = 0; i < 4; ++i) {
            int cid = tid + i * 256;
            int row = cid >> 3, c8 = cid & 7;
            int c8s = c8 ^ (row & 7);
            gl_lds16(Bw + (long long)(bn * 128 + row) * K + kt + c8s * 8,
                     &lds[1][cid * 8]);
        }
    };

    auto compute = [&]() {
#pragma unroll
        for (int kk = 0; kk < 2; ++kk) {
            bf16x8 af[4], bfr[4];
#pragma unroll
            for (int mi = 0; mi < 4; ++mi) {
                int row = wr * 64 + mi * 16 + l15;
                int idx8 = (kk * 4 + l4) ^ (row & 7);
                af[mi] = *(const bf16x8*)&lds[0][row * 64 + idx8 * 8];
            }
#pragma unroll
            for (int ni = 0; ni < 4; ++ni) {
                int row = wc * 64 + ni * 16 + l15;
                int idx8 = (kk * 4 + l4) ^ (row & 7);
                bfr[ni] = *(const bf16x8*)&lds[1][row * 64 + idx8 * 8];
            }
#pragma unroll
            for (int mi = 0; mi < 4; ++mi)
#pragma unroll
                for (int ni = 0; ni < 4; ++ni)
                    acc[mi][ni] = __builtin_amdgcn_mfma_f32_16x16x32_bf16(af[mi], bfr[ni], acc[mi][ni], 0, 0, 0);
        }
    };

    stage(0);
    asm volatile("s_waitcnt vmcnt(0)" ::: "memory");
    __syncthreads();
    for (int kt = 64; kt < K; kt += 64) {
        compute();
        __syncthreads();
        stage(kt);
        asm volatile("s_waitcnt vmcnt(0)" ::: "memory");
        __syncthreads();
    }
    compute();

    u16* st = &lds[0][0];            // [64][136]
    float ps = 0.f, pq = 0.f;
#pragma unroll
    for (int p = 0; p < 2; ++p) {
        __syncthreads();
        if (wr == p) {
#pragma unroll
            for (int ni = 0; ni < 4; ++ni) {
                int colL = wc * 64 + ni * 16 + l15;
                int colG = bn * 128 + colL;
                float bv = bias[colG];
#pragma unroll
                for (int mi = 0; mi < 4; ++mi) {
                    const float* xp = x + (long long)colG * 4096 + bm * 128 + p * 64 + mi * 16 + l4 * 4;
                    f32x4 xv = *(const f32x4*)xp;
#pragma unroll
                    for (int r = 0; r < 4; ++r) {
                        float ss = sscale[p * 64 + mi * 16 + l4 * 4 + r];
                        st[(mi * 16 + l4 * 4 + r) * 136 + colL] = f2b(acc[mi][ni][r] * ss + bv + xv[r]);
                    }
                }
            }
        }
        __syncthreads();
        int lr = tid >> 2, q = tid & 3;
        const u16* src = st + lr * 136 + q * 32;
        u16* dst = sT + (long long)(bm * 128 + p * 64 + lr) * 384 + bn * 128 + q * 32;
#pragma unroll
        for (int j = 0; j < 4; ++j) {
            s16x8 v = *(const s16x8*)(src + j * 8);
            *(s16x8*)(dst + j * 8) = v;
#pragma unroll
            for (int e = 0; e < 8; ++e) { float f = b2f((u16)v[e]); ps += f; pq += f * f; }
        }
    }

    for (int off = 32; off; off >>= 1) { ps += __shfl_down(ps, off); pq += __shfl_down(pq, off); }
    __shared__ float rs[4], rq[4];
    if (lane == 0) { rs[wv] = ps; rq[wv] = pq; }
    __syncthreads();
    if (tid == 0) {
        int bid = bz * 96 + bm * 3 + bn;
        part2[bid * 2 + 0] = rs[0] + rs[1] + rs[2] + rs[3];
        part2[bid * 2 + 1] = rq[0] + rq[1] + rq[2] + rq[3];
    }
}

// ---------------- GEMM 128x128 (R10 structure), bf16 or f32-dmajor epilogue
__global__ __launch_bounds__(256, 4)
void gemm_bt_kernel(const u16* __restrict__ A, long long strideA,
                    const u16* __restrict__ Bw, long long strideB,
                    const float* __restrict__ bias,
                    u16* __restrict__ C, long long strideC,
                    float* __restrict__ Cf,
                    const u16* __restrict__ addT, long long strideAdd,
                    int K, int N, int doGelu)
{
    const int tid = threadIdx.x;
    const int lane = tid & 63;
    const int wv = tid >> 6;
    const int wr = wv >> 1, wc = wv & 1;
    const int l15 = lane & 15, l4 = lane >> 4;
    const int bm = blockIdx.x, bn = blockIdx.y, bz = blockIdx.z;

    A  += (long long)bz * strideA;
    Bw += (long long)bz * strideB;
    if (C)    C    += (long long)bz * strideC;
    if (Cf)   Cf   += (long long)bz * strideC;
    if (addT) addT += (long long)bz * strideAdd;

    __shared__ u16 lds[2][128 * 64];   // 32 KB

    f32x4 acc[4][4] = {};

    auto stage = [&](int kt) {
#pragma unroll
        for (int i = 0; i < 4; ++i) {
            int cid = tid + i * 256;
            int row = cid >> 3, c8 = cid & 7;
            int c8s = c8 ^ (row & 7);
            gl_lds16(A + (long long)(bm * 128 + row) * K + kt + c8s * 8,
                     &lds[0][cid * 8]);
        }
#pragma unroll
        for (int i = 0; i < 4; ++i) {
            int cid = tid + i * 256;
            int row = cid >> 3, c8 = cid & 7;
            int c8s = c8 ^ (row & 7);
            gl_lds16(Bw + (long long)(bn * 128 + row) * K + kt + c8s * 8,
                     &lds[1][cid * 8]);
        }
    };

    auto compute = [&]() {
#pragma unroll
        for (int kk = 0; kk < 2; ++kk) {
            bf16x8 af[4], bfr[4];
#pragma unroll
            for (int mi = 0; mi < 4; ++mi) {
                int row = wr * 64 + mi * 16 + l15;
                int idx8 = (kk * 4 + l4) ^ (row & 7);
                af[mi] = *(const bf16x8*)&lds[0][row * 64 + idx8 * 8];
            }
#pragma unroll
            for (int ni = 0; ni < 4; ++ni) {
                int row = wc * 64 + ni * 16 + l15;
                int idx8 = (kk * 4 + l4) ^ (row & 7);
                bfr[ni] = *(const bf16x8*)&lds[1][row * 64 + idx8 * 8];
            }
#pragma unroll
            for (int mi = 0; mi < 4; ++mi)
#pragma unroll
                for (int ni = 0; ni < 4; ++ni)
                    acc[mi][ni] = __builtin_amdgcn_mfma_f32_16x16x32_bf16(af[mi], bfr[ni], acc[mi][ni], 0, 0, 0);
        }
    };

    stage(0);
    asm volatile("s_waitcnt vmcnt(0)" ::: "memory");
    __syncthreads();
    for (int kt = 64; kt < K; kt += 64) {
        compute();
        __syncthreads();
        stage(kt);
        asm volatile("s_waitcnt vmcnt(0)" ::: "memory");
        __syncthreads();
    }
    compute();

    if (!Cf) {
        u16* st = &lds[0][0];            // [64][136]
#pragma unroll
        for (int p = 0; p < 2; ++p) {
            __syncthreads();
            if (wr == p) {
#pragma unroll
                for (int ni = 0; ni < 4; ++ni) {
                    int colL = wc * 64 + ni * 16 + l15;
                    float bv = bias ? bias[bn * 128 + colL] : 0.f;
#pragma unroll
                    for (int mi = 0; mi < 4; ++mi) {
#pragma unroll
                        for (int r = 0; r < 4; ++r) {
                            float v = acc[mi][ni][r] + bv;
                            if (doGelu) v = gelu_fast(v);
                            st[(mi * 16 + l4 * 4 + r) * 136 + colL] = f2b(v);
                        }
                    }
                }
            }
            __syncthreads();
            int lr = tid >> 2, q = tid & 3;
            const u16* src = st + lr * 136 + q * 32;
            u16* dst = C + (long long)(bm * 128 + p * 64 + lr) * N + bn * 128 + q * 32;
#pragma unroll
            for (int j = 0; j < 4; ++j)
                *(s16x8*)(dst + j * 8) = *(const s16x8*)(src + j * 8);
        }
    } else {
        float* stf = (float*)&lds[0][0];   // [32][132]
#pragma unroll
        for (int p = 0; p < 4; ++p) {
            __syncthreads();
            if (wc == (p >> 1)) {
#pragma unroll
                for (int nj = 0; nj < 2; ++nj) {
                    int ni = (p & 1) * 2 + nj;
                    int colL = wc * 64 + ni * 16 + l15;
                    int lc = nj * 16 + l15;
                    float bv = bias ? bias[bn * 128 + colL] : 0.f;
#pragma unroll
                    for (int mi = 0; mi < 4; ++mi) {
                        int row0 = wr * 64 + mi * 16 + l4 * 4;
#pragma unroll
                        for (int r = 0; r < 4; ++r) {
                            float v = acc[mi][ni][r] + bv
                                    + b2f(addT[(long long)(bm * 128 + row0 + r) * N + bn * 128 + colL]);
                            stf[lc * 132 + row0 + r] = v;
                        }
                    }
                }
            }
            __syncthreads();
            int lc = tid >> 3, q = tid & 7;
            float* dst = Cf + (long long)(bn * 128 + p * 32 + lc) * 4096 + bm * 128 + q * 16;
            const float* src = stf + lc * 132 + q * 16;
#pragma unroll
            for (int j = 0; j < 4; ++j)
                *(f32x4*)(dst + j * 4) = *(const f32x4*)(src + j * 4);
        }
    }
}

// ---------------- per-batch sum / sumsq partials over 1572864 f32 elems
__global__ __launch_bounds__(256)
void stats_part_kernel(const float* __restrict__ x, float* __restrict__ part)
{
    int b = blockIdx.x, cb = blockIdx.y, t = threadIdx.x;
    const float* p = x + (long long)b * PX + (long long)cb * 49152;
    float s = 0.f, q = 0.f;
    for (int i = 0; i < 48; ++i) {
        f32x4 v = *(const f32x4*)(p + (i * 256 + t) * 4);
#pragma unroll
        for (int j = 0; j < 4; ++j) { s += v[j]; q += v[j] * v[j]; }
    }
    for (int off = 32; off; off >>= 1) { s += __shfl_down(s, off); q += __shfl_down(q, off); }
    __shared__ float rs[4], rq[4];
    if ((t & 63) == 0) { rs[t >> 6] = s; rq[t >> 6] = q; }
    __syncthreads();
    if (t == 0) {
        part[(b * 32 + cb) * 2 + 0] = rs[0] + rs[1] + rs[2] + rs[3];
        part[(b * 32 + cb) * 2 + 1] = rq[0] + rq[1] + rq[2] + rq[3];
    }
}

__global__ void stats_fin_kernel(const float* __restrict__ part, float* __restrict__ mu, float* __restrict__ rsg)
{
    int b = blockIdx.x, l = threadIdx.x;
    float s = l < 32 ? part[(b * 32 + l) * 2 + 0] : 0.f;
    float q = l < 32 ? part[(b * 32 + l) * 2 + 1] : 0.f;
    for (int off = 32; off; off >>= 1) { s += __shfl_down(s, off); q += __shfl_down(q, off); }
    if (l == 0) {
        float m = s / 1572864.f;
        float v = q / 1572864.f - m * m; v = fmaxf(v, 0.f);
        mu[b] = m; rsg[b] = rsqrtf(v + 1e-5f);
    }
}

// ---------------- LN1 apply (f32 src, d-major) -> T-layout bf16
__global__ __launch_bounds__(256)
void ln_apply_T_kernel(const float* __restrict__ src, const float* __restrict__ w, const float* __restrict__ bb,
                       const float* __restrict__ mu, const float* __restrict__ rsg, u16* __restrict__ dstT)
{
    int nt = blockIdx.x, dt = blockIdx.y, b = blockIdx.z;
    int t = threadIdx.x, tx = t & 63, ty = t >> 6;
    __shared__ float tile[64][65];
    float m = mu[b], r = rsg[b];
    const long long base = (long long)b * PX;
#pragma unroll 4
    for (int i = 0; i < 16; ++i) {
        int dy = ty + i * 4;
        int d = dt * 64 + dy, n = nt * 64 + tx;
        long long widx = (long long)d * 4096 + n;
        tile[dy][tx] = (src[base + widx] - m) * r * w[widx] + bb[widx];
    }
    __syncthreads();
#pragma unroll 4
    for (int i = 0; i < 16; ++i) {
        int ny = ty + i * 4;
        int n = nt * 64 + ny, d = dt * 64 + tx;
        dstT[base + (long long)n * 384 + d] = f2b(tile[tx][ny]);
    }
}

// ---------------- KV partials via MFMA, no-max exp (inputs bounded), CHUNK=128
__global__ __launch_bounds__(256)
void kv_part_kernel(const u16* __restrict__ KT, const u16* __restrict__ VT,
                    u16* __restrict__ KVp, float* __restrict__ sp)
{
    const int ch = blockIdx.x, h = blockIdx.y, b = blockIdx.z;
    const int t = threadIdx.x;
    const int lane = t & 63, w = t >> 6;

    __shared__ u16 kraw[128 * 64];
    __shared__ u16 eKT[64 * 128];
    __shared__ u16 Vt[32 * 128];
    __shared__ float reds[4][64];

    const u16* Kp = KT + (long long)b * PQ + (long long)(ch * 128) * 768 + h * 64;
    const u16* Vp = VT + (long long)b * PX + (long long)(ch * 128) * 384 + h * 32;

#pragma unroll
    for (int pass = 0; pass < 4; ++pass) {
        int cid = t + pass * 256;
        int row = cid >> 3, c8 = cid & 7;
        gl_lds16(Kp + (long long)row * 768 + c8 * 8, kraw + cid * 8);
    }

    {
        int v0 = (t & 7) * 4;
#pragma unroll
        for (int pass = 0; pass < 4; ++pass) {
            int n = (t >> 3) + pass * 32;
            s16x4 v4 = *(const s16x4*)(Vp + (long long)n * 384 + v0);
#pragma unroll
            for (int j = 0; j < 4; ++j) {
                int row = v0 + j;
                Vt[row * 128 + (n ^ ((row & 7) << 3))] = (u16)v4[j];
            }
        }
    }

    asm volatile("s_waitcnt vmcnt(0)" ::: "memory");
    __syncthreads();

    const int c = lane;
    {
        float s = 0.f;
        const int swz = (c & 7) << 3;
#pragma unroll
        for (int r8 = 0; r8 < 4; ++r8) {
            int rbase = w * 32 + r8 * 8;
            s16x8 buf;
#pragma unroll
            for (int j = 0; j < 8; ++j) {
                float e = __expf(b2f(kraw[(rbase + j) * 64 + c]));
                s += e;
                buf[j] = (short)f2b(e);
            }
            *(s16x8*)&eKT[c * 128 + (rbase ^ swz)] = buf;
        }
        reds[w][c] = s;
    }
    __syncthreads();

    if (t < 64)
        sp[((long long)(b * 12 + h) * 32 + ch) * 64 + t] =
            reds[0][t] + reds[1][t] + reds[2][t] + reds[3][t];

    const int l15 = lane & 15, l4 = lane >> 4;
    const int qrow = w * 16 + l15;
    const int sa = (qrow & 7) << 3;
    const int v0row = l15, v1row = 16 + l15;
    const int s0 = (v0row & 7) << 3, s1 = (v1row & 7) << 3;
    f32x4 acc0 = {}, acc1 = {};
#pragma unroll
    for (int ns = 0; ns < 4; ++ns) {
        int na = ns * 32 + l4 * 8;
        bf16x8 a  = *(const bf16x8*)&eKT[qrow * 128 + (na ^ sa)];
        bf16x8 b0 = *(const bf16x8*)&Vt[v0row * 128 + (na ^ s0)];
        bf16x8 b1 = *(const bf16x8*)&Vt[v1row * 128 + (na ^ s1)];
        acc0 = __builtin_amdgcn_mfma_f32_16x16x32_bf16(a, b0, acc0, 0, 0, 0);
        acc1 = __builtin_amdgcn_mfma_f32_16x16x32_bf16(a, b1, acc1, 0, 0, 0);
    }
    u16* Kb = KVp + ((long long)(b * 12 + h) * 32 + ch) * 2048;
#pragma unroll
    for (int r = 0; r < 4; ++r) {
        int q = w * 16 + l4 * 4 + r;
        Kb[q * 32 + l15]      = f2b(acc0[r]);
        Kb[q * 32 + 16 + l15] = f2b(acc1[r]);
    }
}

// ---------------- merge KV partials AND fold head-unification:
// per (h,b): kvq[q][v] = KV/(s*4096); Wcomb[:, h*64..+64) = huw[:,h*32..+32) @ kvq^T
__global__ __launch_bounds__(256)
void kv_fin_kernel(const u16* __restrict__ KVp, const float* __restrict__ sp,
                   const u16* __restrict__ huwB, u16* __restrict__ Wcomb)
{
    const int h = blockIdx.x, b = blockIdx.y;
    const int t = threadIdx.x;
    const int lane = t & 63, w = t >> 6;
    const int l15 = lane & 15, l4 = lane >> 4;

    __shared__ float fac[64];
    __shared__ u16 kvq[64 * 40];    // [q][v], padded stride 40
    __shared__ u16 hw[384 * 40];    // [o][v-slice], padded stride 40

    // load huw slice: rows 0..383, cols h*32..h*32+32
    for (int i = t; i < 384 * 4; i += 256) {
        int row = i >> 2, seg = i & 3;
        *(s16x8*)&hw[row * 40 + seg * 8] =
            *(const s16x8*)(huwB + row * 384 + h * 32 + seg * 8);
    }

    const long long pb = (long long)(b * 12 + h) * 32;
    if (t < 64) {
        float s = 0.f;
#pragma unroll
        for (int ch = 0; ch < 32; ++ch) s += sp[(pb + ch) * 64 + t];
        fac[t] = 1.f / (s * 4096.f);
    }
    __syncthreads();

    // kvq[q][v] = (sum of KV partials) * fac[q]
    {
        const int v0 = (t & 3) * 8, q = t >> 2;
        float acc[8] = {};
#pragma unroll
        for (int ch = 0; ch < 32; ++ch) {
            s16x8 kv8 = *(const s16x8*)&KVp[(pb + ch) * 2048 + q * 32 + v0];
#pragma unroll
            for (int j = 0; j < 8; ++j) acc[j] += b2f((u16)kv8[j]);
        }
        float fq = fac[q];
        s16x8 o;
#pragma unroll
        for (int j = 0; j < 8; ++j) o[j] = (short)f2b(acc[j] * fq);
        *(s16x8*)&kvq[q * 40 + v0] = o;
    }
    __syncthreads();

    // MFMA: wave w owns output rows w*96..+96 (6 M-tiles) x 64 cols (4 N-tiles), K=32
    bf16x8 af[6], bfr[4];
#pragma unroll
    for (int mi = 0; mi < 6; ++mi)
        af[mi] = *(const bf16x8*)&hw[(w * 96 + mi * 16 + l15) * 40 + l4 * 8];
#pragma unroll
    for (int ni = 0; ni < 4; ++ni)
        bfr[ni] = *(const bf16x8*)&kvq[(ni * 16 + l15) * 40 + l4 * 8];
    f32x4 acc[6][4] = {};
#pragma unroll
    for (int mi = 0; mi < 6; ++mi)
#pragma unroll
        for (int ni = 0; ni < 4; ++ni)
            acc[mi][ni] = __builtin_amdgcn_mfma_f32_16x16x32_bf16(af[mi], bfr[ni], acc[mi][ni], 0, 0, 0);

    u16* Wb = Wcomb + (long long)b * 294912;
#pragma unroll
    for (int mi = 0; mi < 6; ++mi) {
#pragma unroll
        for (int ni = 0; ni < 4; ++ni) {
            int col = h * 64 + ni * 16 + l15;
#pragma unroll
            for (int r = 0; r < 4; ++r) {
                int o = w * 96 + mi * 16 + l4 * 4 + r;
                Wb[o * 768 + col] = f2b(acc[mi][ni][r]);
            }
        }
    }
}

// ---------------- transpose LN2 weight/bias (f32 d-major) -> bf16 T-layout
__global__ __launch_bounds__(256)
void wtrans_kernel(const float* __restrict__ w, const float* __restrict__ bb,
                   u16* __restrict__ wT, u16* __restrict__ bT)
{
    int nt = blockIdx.x, dt = blockIdx.y;
    const float* src = blockIdx.z ? bb : w;
    u16* dst = blockIdx.z ? bT : wT;
    int t = threadIdx.x, tx = t & 63, ty = t >> 6;
    __shared__ float tile[64][65];
#pragma unroll 4
    for (int i = 0; i < 16; ++i) {
        int dy = ty + i * 4;
        tile[dy][tx] = src[(long long)(dt * 64 + dy) * 4096 + nt * 64 + tx];
    }
    __syncthreads();
#pragma unroll 4
    for (int i = 0; i < 16; ++i) {
        int ny = ty + i * 4;
        dst[(long long)(nt * 64 + ny) * 384 + dt * 64 + tx] = f2b(tile[tx][ny]);
    }
}

// ---------------- LN2 stats finalize from 96 partials/batch
__global__ __launch_bounds__(256)
void stats_fin2_kernel(const float* __restrict__ part2, float* __restrict__ mu, float* __restrict__ rsg)
{
    int b = blockIdx.x, t = threadIdx.x;
    float s = 0.f, q = 0.f;
    if (t < 96) { s = part2[(b * 96 + t) * 2]; q = part2[(b * 96 + t) * 2 + 1]; }
    for (int off = 32; off; off >>= 1) { s += __shfl_down(s, off); q += __shfl_down(q, off); }
    __shared__ float rs[4], rq[4];
    if ((t & 63) == 0) { rs[t >> 6] = s; rq[t >> 6] = q; }
    __syncthreads();
    if (t == 0) {
        float S = rs[0] + rs[1] + rs[2] + rs[3], Q = rq[0] + rq[1] + rq[2] + rq[3];
        float m = S / 1572864.f;
        float v = Q / 1572864.f - m * m; v = fmaxf(v, 0.f);
        mu[b] = m; rsg[b] = rsqrtf(v + 1e-5f);
    }
}

// ---------------- LN2 apply: elementwise T-layout, all bf16
__global__ __launch_bounds__(256)
void ln2_apply_kernel(const u16* __restrict__ sT, const u16* __restrict__ wT, const u16* __restrict__ bT,
                      const float* __restrict__ mu, const float* __restrict__ rsg, u16* __restrict__ x2T)
{
    int blk = blockIdx.x, b = blockIdx.y, t = threadIdx.x;
    float m = mu[b], r = rsg[b];
    long long wi = (long long)blk * 2048 + t * 8;
    long long gi = (long long)b * PX + wi;
    s16x8 sv = *(const s16x8*)(sT + gi);
    s16x8 wv = *(const s16x8*)(wT + wi);
    s16x8 bv = *(const s16x8*)(bT + wi);
    s16x8 o;
#pragma unroll
    for (int j = 0; j < 8; ++j)
        o[j] = (short)f2b((b2f((u16)sv[j]) - m) * r * b2f((u16)wv[j]) + b2f((u16)bv[j]));
    *(s16x8*)(x2T + gi) = o;
}

extern "C" void kernel_launch(void* const* d_in, const int* in_sizes, int n_in,
                              void* d_out, int out_size, void* d_ws, size_t ws_size,
                              hipStream_t stream)
{
    const float* x    = (const float*)d_in[0];
    const float* ln1w = (const float*)d_in[1];
    const float* ln1b = (const float*)d_in[2];
    const float* qw   = (const float*)d_in[3];
    const float* qb   = (const float*)d_in[4];
    const float* kw   = (const float*)d_in[5];
    const float* kb   = (const float*)d_in[6];
    const float* vw   = (const float*)d_in[7];
    const float* vb   = (const float*)d_in[8];
    const float* huw  = (const float*)d_in[9];
    const float* hub  = (const float*)d_in[10];
    const float* ln2w = (const float*)d_in[11];
    const float* ln2b = (const float*)d_in[12];
    const float* ff1w = (const float*)d_in[13];
    const float* ff1b = (const float*)d_in[14];
    const float* ff2w = (const float*)d_in[15];
    const float* ff2b = (const float*)d_in[16];
    float* out = (float*)d_out;

    char* ws = (char*)d_ws;
    u16*   aT    = (u16*)(ws + 0);                 //  50.3 MB region A
    u16*   QT    = (u16*)(ws + 50331648LL);        // 100.7 MB region B
    u16*   KT    = (u16*)(ws + 150994944LL);       // 100.7 MB region C
    u16*   VT    = (u16*)(ws + 251658240LL);       //  50.3 MB region D
    float* rsump = (float*)(ws + 301989888LL);     //   1.6 MB region E (ex-WeffT)
    u16*   wcv   = (u16*)(ws + 311427072LL);       //   4.1 MB
    float* fbuf  = (float*)(ws + 315555840LL);     //  ~64 KB

    // region A overlays (aT dead after QKV GEMM):
    u16*   KVp    = (u16*)(ws + 0);                // 25,165,824 B
    float* sp     = (float*)(ws + 25165824LL);     //  1,572,864 B
    u16*   WcombB = (u16*)(ws + 27525120LL);       //  9,437,184 B

    // region C overlays (KT dead after kv_part):
    u16* sT = KT;                                       // 50.3 MB
    u16* wT = (u16*)(ws + 150994944LL + 50331648LL);    //  3.1 MB
    u16* bT = (u16*)(ws + 150994944LL + 53477376LL);    //  3.1 MB
    u16* g8 = KT;                                       // 100.66 MB (after ln2_apply)

    u16* x2T = QT;

    u16* qwB   = wcv;        // rows 0..1919 of the fused qkv weight
    u16* ff1wB = wcv + 884736;
    u16* ff2wB = wcv + 1474560;
    u16* huwB  = wcv + 737280;

    float* part1 = fbuf;               // 1024
    float* mu1   = fbuf + 1024;        // 16
    float* rs1   = fbuf + 1040;        // 16
    float* part2 = fbuf + 1056;        // 3072 (96*16*2)
    float* mu2   = part2 + 3072;       // 16
    float* rs2   = mu2 + 16;           // 16
    float* qkvb  = rs2 + 16;           // 1920

    wconv_kernel<<<2016, 256, 0, stream>>>(qw, kw, vw, huw, ff1w, ff2w, wcv);
    bcat_kernel<<<8, 256, 0, stream>>>(qb, kb, vb, qkvb);

    stats_part_kernel<<<dim3(16, 32), 256, 0, stream>>>(x, part1);
    stats_fin_kernel<<<16, 64, 0, stream>>>(part1, mu1, rs1);
    ln_apply_T_kernel<<<dim3(64, 6, 16), 256, 0, stream>>>(x, ln1w, ln1b, mu1, rs1, aT);

    // fused Q|K|V projection (exp(Q) + softmax row-sum partials fused in)
    gemm_qkv_kernel<<<dim3(32, 15, 16), 256, 0, stream>>>(aT, PX, qwB, qkvb, QT, KT, VT, rsump, 384);

    kv_part_kernel<<<dim3(32, 12, 16), 256, 0, stream>>>(KT, VT, KVp, sp);

    // kv merge + head-unification fold -> Wcomb (replaces WeffT + wcomb GEMM)
    kv_fin_kernel<<<dim3(12, 16), 256, 0, stream>>>(KVp, sp, huwB, WcombB);

    wtrans_kernel<<<dim3(64, 6, 2), 256, 0, stream>>>(ln2w, ln2b, wT, bT);

    // attn GEMM: softmax-scale + hub + x residual + LN2 partials fused
    gemm_attn_kernel<<<dim3(32, 3, 16), 256, 0, stream>>>(QT, PQ, WcombB, 294912, hub, x, rsump, sT, part2, 768);

    stats_fin2_kernel<<<16, 256, 0, stream>>>(part2, mu2, rs2);
    ln2_apply_kernel<<<dim3(768, 16), 256, 0, stream>>>(sT, wT, bT, mu2, rs2, x2T);

    // FFN in 2 chunks of 8 batches (region C free after ln2_apply)
    for (int c = 0; c < 2; ++c) {
        gemm_bt_kernel<<<dim3(32, 12, 8), 256, 0, stream>>>(
            x2T + (long long)c * 8 * PX, PX, ff1wB, 0, ff1b,
            g8, PH, nullptr, nullptr, 0, 384, 1536, 1);
        gemm_bt_kernel<<<dim3(32, 3, 8), 256, 0, stream>>>(
            g8, PH, ff2wB, 0, ff2b,
            nullptr, PX, out + (long long)c * 8 * PX,
            x2T + (long long)c * 8 * PX, PX, 1536, 384, 0);
    }
}